// Round 6
// baseline (2948.932 us; speedup 1.0000x reference)
//
#include <hip/hip_runtime.h>
#include <math.h>

// ---------------- problem constants ----------------
#define HC 96
#define WC 96
#define CCH 64
#define BB 8
#define NL 8
#define IMG (HC*WC)                 // 9216
#define LSTRIDE (BB*CCH*IMG)        // 4,718,592
#define EPS 1e-5f

// padded-chunked NHWC bf16 layout: [b][ch2][y:98][x:98][ic:32]
#define PY 98
#define PX 98
#define ICH 32
#define PLANE (PY*PX*ICH)           // 307,328
#define PL (BB*2*PLANE)             // 4,917,248 els per layer tensor
#define APK_L (2*9*2*64*32)         // 73,728 els per layer per direction

typedef __bf16 bf16;
typedef bf16 bf16x8 __attribute__((ext_vector_type(8)));
typedef float f32x4 __attribute__((ext_vector_type(4)));

__device__ __forceinline__ float a_of(int i){ return sqrtf((i+1.f)/(i+2.f)); }
__device__ __forceinline__ float b_of(int i){ return sqrtf((float)i/(float)(i+1)); }

// ---------------------------------------------------------------------------
// Split weights into hi/lo bf16 planes, frag-friendly layout:
// apX[l][ch][tap][rep][oc64][ic32]. fwd: K[l][oc][ic][tap]; bwd: K[l][ic][oc][8-tap].
__global__ void pack_weights(const float* __restrict__ K,
                             bf16* __restrict__ apf, bf16* __restrict__ apb){
  int idx = blockIdx.x*256 + threadIdx.x;          // NL*9*64*64
  if (idx >= NL*9*64*64) return;
  int ic = idx & 63, oc = (idx>>6) & 63;
  int tap = (idx>>12) % 9, l = idx/(4096*9);
  float wf = K[(((size_t)l*64 + oc)*64 + ic)*9 + tap];
  float wb = K[(((size_t)l*64 + ic)*64 + oc)*9 + (8-tap)];
  int ch = ic>>5, ic5 = ic&31;
  size_t base = (size_t)l*APK_L + ((size_t)((ch*9 + tap)*2)*64 + oc)*32 + ic5;
  bf16 fh = (bf16)wf;
  apf[base] = fh; apf[base + 64*32] = (bf16)(wf - (float)fh);
  bf16 bh = (bf16)wb;
  apb[base] = bh; apb[base + 64*32] = (bf16)(wb - (float)bh);
}

// ---------------------------------------------------------------------------
// Fix-iter 0 constant-folded: Yf closed form from X, X0; writes padded NHWC bf16.
__global__ __launch_bounds__(256) void init_yf_t(const float* __restrict__ X,
                                                 const float* __restrict__ X0,
                                                 bf16* __restrict__ yfq){
  __shared__ float LX[64][97];
  __shared__ float L0[64][97];
  int b = blockIdx.y, y = blockIdx.x;
  for (int i = threadIdx.x; i < 64*96; i += 256){
    int c = i/96, x = i%96;
    LX[c][x] = X[(((size_t)b*64 + c)*96 + y)*96 + x];
    L0[c][x] = X0[((size_t)c*96 + y)*96 + x];
  }
  __syncthreads();
  for (int j = threadIdx.x; j < 96*64; j += 256){
    int x = j>>6, c = j&63;
    float xv = LX[c][x], x0v = L0[c][x];
    size_t eoff = ((size_t)(b*2 + (c>>5))*PY + (y+1))*(size_t)PX*ICH
                + (size_t)(x+1)*ICH + (c&31);
    float yf = 0.f;
#pragma unroll
    for (int i = 0; i < NL; i++){
      float yv = (i==0 ? x0v : 0.f) + (i==NL-1 ? xv : 0.f);
      yf = a_of(i)*(b_of(i)*yf + yv);
      yfq[(size_t)i*PL + eoff] = (bf16)yf;
    }
  }
}

// ---------------------------------------------------------------------------
// Backward scan in place over padded bf16 Yf->Z (pads are 0 and map to 0).
__global__ __launch_bounds__(256) void back_scan_q(bf16* __restrict__ buf){
  size_t base = ((size_t)blockIdx.x*256 + threadIdx.x)*8;
  float c[8];
#pragma unroll
  for (int e=0;e<8;e++) c[e]=0.f;
#pragma unroll
  for (int l = NL-1; l >= 0; l--){
    float al = a_of(l);
    uint4 v = *(const uint4*)(buf + (size_t)l*PL + base);
    bf16* h = (bf16*)&v;
    uint4 o; bf16* ho = (bf16*)&o;
#pragma unroll
    for (int e=0;e<8;e++){
      float z = al*(al*c[e] + (float)h[e]);
      ho[e] = (bf16)z; c[e] = z;
    }
    *(uint4*)(buf + (size_t)l*PL + base) = o;
  }
}

// Final backward scan: fp32 NCHW in zbase (d_out), emits out0 = Z[7].
__global__ __launch_bounds__(256) void back_scan_final(float* __restrict__ zbase,
                                                       float* __restrict__ out0){
  int idx = blockIdx.x*256 + threadIdx.x;
  float c = 0.f;
#pragma unroll
  for (int i = NL-1; i >= 0; i--){
    float ai = a_of(i);
    float z = ai*(ai*c + zbase[(size_t)i*LSTRIDE + idx]);
    zbase[(size_t)i*LSTRIDE + idx] = z;
    if (i == NL-1) out0[idx] = z;
    c = z;
  }
}

// ---------------------------------------------------------------------------
// Staging helpers for conv_mfma.
__device__ __forceinline__ void stageB_raw(const bf16* inq, char* Bbc,
                                           int b, int ch, int y0, int tid){
  const uint4* src = (const uint4*)(inq + (size_t)(b*2 + ch)*PLANE
                                        + (size_t)y0*PX*ICH);
  for (int i = tid; i < 1568; i += 256){
    int r = i / 392, rem = i - r*392;        // 392 uint4 per padded row
    int px = rem >> 2, slot = rem & 3;
    int s = (px & 3) ^ ((px >> 2) & 3);
    *(uint4*)(Bbc + (size_t)r*6272 + (size_t)px*64 + ((slot ^ s)<<4)) = src[i];
  }
}

__device__ __forceinline__ void stageB_norm(const float* dzf_in, const float2* stat_s,
                                            char* Bbc, int b, int ch, int y0, int tid){
  for (int i = tid; i < 1568; i += 256){
    int r = i / 392, rem = i - r*392;
    int px = rem >> 2, slot = rem & 3;
    int s = (px & 3) ^ ((px >> 2) & 3);
    int y = y0 - 1 + r;
    int x = px - 1;
    union { uint4 v; unsigned short u[8]; } o;
    if (y >= 0 && y < 96 && x >= 0 && x < 96){
      const float* sp = dzf_in + (((size_t)(b*96 + y)*96 + x)*64 + ch*32 + slot*8);
      f32x4 v0 = *(const f32x4*)sp;
      f32x4 v1 = *(const f32x4*)(sp + 4);
#pragma unroll
      for (int k=0;k<8;k++){
        float2 mr = stat_s[ch*32 + slot*8 + k];
        float f = (k < 4) ? v0[k] : v1[k-4];
        float v = (f - mr.x)*mr.y;
        v = (v >= 0.f) ? v : 0.2f*v;
        bf16 hh = (bf16)v;
        o.u[k] = *(unsigned short*)&hh;
      }
    } else {
      o.v = make_uint4(0u,0u,0u,0u);
    }
    *(uint4*)(Bbc + (size_t)r*6272 + (size_t)px*64 + ((slot ^ s)<<4)) = o.v;
  }
}

// A chunks: global chunk index = tap*2+rep (256 u4 each; h half = 128 u4).
// NE = elements staged (chunks*128). Load into regs early, write after barrier.
template<int NE>
__device__ __forceinline__ void loadA(uint4* pA, const bf16* apk,
                                      int ch, int h, int c0, int tid){
  const uint4* srcA = (const uint4*)(apk + (size_t)ch*36864);
#pragma unroll
  for (int j = 0; j*256 < NE; j++){
    int idx = tid + j*256;
    int lc = idx >> 7, jj = idx & 127;
    pA[j] = srcA[(size_t)(c0 + lc)*256 + h*128 + jj];
  }
}
template<int NE>
__device__ __forceinline__ void writeA(const uint4* pA, char* Abc, int tid){
#pragma unroll
  for (int j = 0; j*256 < NE; j++){
    int idx = tid + j*256;
    int lc = idx >> 7, jj = idx & 127;
    int oc = jj >> 2, slot = jj & 3;
    int s = (oc & 3) ^ ((oc >> 2) & 3);
    *(uint4*)(Abc + (size_t)lc*2048 + (size_t)oc*64 + ((slot ^ s)<<4)) = pA[j];
  }
}
// Direct (non-prefetched) A stage for the prologue.
template<int NE>
__device__ __forceinline__ void stageA(const bf16* apk, char* Abc,
                                       int ch, int h, int c0, int tid){
  const uint4* srcA = (const uint4*)(apk + (size_t)ch*36864);
#pragma unroll
  for (int j = 0; j*256 < NE; j++){
    int idx = tid + j*256;
    int lc = idx >> 7, jj = idx & 127;
    int oc = jj >> 2, slot = jj & 3;
    int s = (oc & 3) ^ ((oc >> 2) & 3);
    *(uint4*)(Abc + (size_t)lc*2048 + (size_t)oc*64 + ((slot ^ s)<<4))
        = srcA[(size_t)(c0 + lc)*256 + h*128 + jj];
  }
}

// ---------------------------------------------------------------------------
// MFMA implicit-GEMM 3x3 conv, pad=1, 2-pass split weights (Wh+Wl)*bf16(in).
// R6 restructure (latency-bound fix):
//  * A split by TAP GROUP (taps 0-4 / 5-8, both reps together) so each B
//    fragment feeds both hi- and lo-plane MFMA: 126 ds_read_b128/wave/conv
//    (R5's rep split re-read B: 180).
//  * T14 async-STAGE: each phase issues the next phase's global loads into
//    registers BEFORE its MFMA cluster; ds_writes happen after the barrier.
//    B(ch1) (MODE 0, raw bf16) is prefetched TWO phases ahead (~700cy hide).
//    MODE 1/2 stage B directly with fused normalize+lrelu+quantize.
//  * LDS 45.6 KB (B 25088 + A 20480) -> 3 blocks/CU, grid 768 = 3*256.
// Block: 32 oc (h=blockIdx.z half) x (2 rows x 96 cols); wave = 2 mt x 3 nt.
// MODE 0: in=Zq[l] bf16 padded -> dZf (NHWC fp32, LDS transpose) + stats
// MODE 1: in=dZf+stats; yv=-acc(+X/+X0); yf=a*(b*prev_q+yv) -> Yfq bf16 padded
// MODE 2: in=dZf+stats; same math fp32, direct NCHW stores to zbase (final it)
template<int MODE>
__global__ __launch_bounds__(256, 3) void conv_mfma(
    const bf16* __restrict__ inq, const float* __restrict__ dzf_in,
    const bf16* __restrict__ apk,
    float* __restrict__ outF, float* __restrict__ accstat,
    bf16* __restrict__ yfq_out, const bf16* __restrict__ yfq_prev,
    float* __restrict__ zb_out, const float* __restrict__ zb_prev,
    const float* __restrict__ Xadd, const float* __restrict__ X0add,
    float a_i, float b_i)
{
  __shared__ __align__(16) char smem[25088 + 20480];
  char* Bbc = smem;                        // [4 rows][98 px][32 ic] bf16, swizzled
  char* Abc = smem + 25088;                // [<=10 chunks][32 oc][32 ic] bf16, swz
  __shared__ float2 stat_s[64];            // per-channel (m, rstd) for MODE>=1

  const int rowg = blockIdx.x, b = blockIdx.y, h = blockIdx.z;  // h = oc half
  const int y0 = rowg*2;
  const int tid = threadIdx.x;
  const int w = tid>>6, lane = tid&63;
  const int n16 = lane&15, q = lane>>4;
  const int wr = w>>1, wcol = (w&1)*48;
  const int yg = y0 + wr;

  if (MODE >= 1){   // finalize instance-norm stats for this b
    if (tid < 64){
      float s  = accstat[((size_t)b*64 + tid)*2];
      float s2 = accstat[((size_t)b*64 + tid)*2 + 1];
      float m = s*(1.f/IMG);
      float vv = s2*(1.f/IMG) - m*m;
      if (vv < 0.f) vv = 0.f;
      stat_s[tid] = make_float2(m, rsqrtf(vv + EPS));
    }
    __syncthreads();
  }

  f32x4 acc[2][3];
#pragma unroll
  for (int a=0;a<2;a++)
#pragma unroll
    for (int c=0;c<3;c++){ f32x4 z = {0.f,0.f,0.f,0.f}; acc[a][c] = z; }

// one tap-group MFMA pass over LDS-resident A chunks (local chunk = t*2+rep)
#define MFMA_PHASE(TS, TC)                                                        \
  _Pragma("unroll")                                                               \
  for (int t = 0; t < (TC); t++){                                                 \
    const int tap = (TS) + t;                                                     \
    const int tg = tap/3, tj = tap%3;                                             \
    bf16x8 Ah[2], Al[2];                                                          \
    _Pragma("unroll")                                                             \
    for (int mt=0;mt<2;mt++){                                                     \
      int oc32 = mt*16 + n16;                                                     \
      int sA = (oc32 & 3) ^ ((oc32 >> 2) & 3);                                    \
      Ah[mt] = *(const bf16x8*)(Abc + (size_t)(t*2+0)*2048 + (size_t)oc32*64 + ((q ^ sA)<<4)); \
      Al[mt] = *(const bf16x8*)(Abc + (size_t)(t*2+1)*2048 + (size_t)oc32*64 + ((q ^ sA)<<4)); \
    }                                                                             \
    bf16x8 Bf[3];                                                                 \
    _Pragma("unroll")                                                             \
    for (int nt=0;nt<3;nt++){                                                     \
      int px = wcol + nt*16 + n16 + tj;                                           \
      int sB = (px & 3) ^ ((px >> 2) & 3);                                        \
      Bf[nt] = *(const bf16x8*)(Bbc + (size_t)(wr + tg)*6272 + (size_t)px*64 + ((q ^ sB)<<4)); \
    }                                                                             \
    _Pragma("unroll")                                                             \
    for (int nt=0;nt<3;nt++)                                                      \
      _Pragma("unroll")                                                           \
      for (int mt=0;mt<2;mt++){                                                   \
        acc[mt][nt] = __builtin_amdgcn_mfma_f32_16x16x32_bf16(Ah[mt], Bf[nt], acc[mt][nt], 0,0,0); \
        acc[mt][nt] = __builtin_amdgcn_mfma_f32_16x16x32_bf16(Al[mt], Bf[nt], acc[mt][nt], 0,0,0); \
      }                                                                           \
  }

  // ---- prologue: B(ch0) + A(ch0, chunks 0..9 = taps 0-4) direct ----
  if (MODE == 0) stageB_raw(inq, Bbc, b, 0, y0, tid);
  else           stageB_norm(dzf_in, stat_s, Bbc, b, 0, y0, tid);
  stageA<1280>(apk, Abc, 0, h, 0, tid);
  __syncthreads();

  uint4 pA[5];
  uint4 pB[7];

  // ---- p0: MFMA(ch0, taps0-4); prefetch A(ch0,tg1) + B(ch1, MODE 0) ----
  loadA<1024>(pA, apk, 0, h, 10, tid);
  if (MODE == 0){
    const uint4* srcB1 = (const uint4*)(inq + (size_t)(b*2 + 1)*PLANE
                                            + (size_t)y0*PX*ICH);
#pragma unroll
    for (int j=0;j<7;j++){
      int idx = tid + j*256;
      pB[j] = (idx < 1568) ? srcB1[idx] : make_uint4(0u,0u,0u,0u);
    }
  }
  MFMA_PHASE(0, 5)
  __syncthreads();
  writeA<1024>(pA, Abc, tid);
  __syncthreads();

  // ---- p1: MFMA(ch0, taps5-8); prefetch A(ch1,tg0); write B(ch1) after ----
  loadA<1280>(pA, apk, 1, h, 0, tid);
  MFMA_PHASE(5, 4)
  __syncthreads();
  if (MODE == 0){
#pragma unroll
    for (int j=0;j<7;j++){
      int idx = tid + j*256;
      if (idx < 1568){
        int r = idx/392, rem = idx - r*392;
        int px = rem >> 2, slot = rem & 3;
        int s = (px & 3) ^ ((px >> 2) & 3);
        *(uint4*)(Bbc + (size_t)r*6272 + (size_t)px*64 + ((slot ^ s)<<4)) = pB[j];
      }
    }
  } else {
    stageB_norm(dzf_in, stat_s, Bbc, b, 1, y0, tid);
  }
  writeA<1280>(pA, Abc, tid);
  __syncthreads();

  // ---- p2: MFMA(ch1, taps0-4); prefetch A(ch1,tg1) ----
  loadA<1024>(pA, apk, 1, h, 10, tid);
  MFMA_PHASE(0, 5)
  __syncthreads();
  writeA<1024>(pA, Abc, tid);
  __syncthreads();

  // ---- p3: MFMA(ch1, taps5-8) ----
  MFMA_PHASE(5, 4)

#undef MFMA_PHASE

  // ---------------- epilogue ----------------
  if (MODE == 0){
    // fused instance-norm partial stats: acc IS dZ for this (oc, yg, 48 px)
    float sv[8], qv[8];
#pragma unroll
    for (int mt=0;mt<2;mt++)
#pragma unroll
      for (int r=0;r<4;r++){
        float a0 = acc[mt][0][r], a1 = acc[mt][1][r], a2 = acc[mt][2][r];
        sv[mt*4+r] = a0 + a1 + a2;
        qv[mt*4+r] = a0*a0 + a1*a1 + a2*a2;
      }
#pragma unroll
    for (int off=1; off<16; off<<=1)
#pragma unroll
      for (int k=0;k<8;k++){
        sv[k] += __shfl_xor(sv[k], off, 64);
        qv[k] += __shfl_xor(qv[k], off, 64);
      }
    if (n16 == 0){
#pragma unroll
      for (int k=0;k<8;k++){
        int oc = h*32 + (k>>2)*16 + q*4 + (k&3);
        atomicAdd(&accstat[((size_t)b*64 + oc)*2    ], sv[k]);
        atomicAdd(&accstat[((size_t)b*64 + oc)*2 + 1], qv[k]);
      }
    }
  }
  if (MODE >= 1){   // yv = -acc (+X at l=7) (+X0 at l=0); coalesced adds (x = lanes)
#pragma unroll
    for (int mt=0;mt<2;mt++)
#pragma unroll
      for (int nt=0;nt<3;nt++){
        const int x = wcol + nt*16 + n16;
#pragma unroll
        for (int r=0;r<4;r++){
          const int oc = h*32 + mt*16 + q*4 + r;
          float v = -acc[mt][nt][r];
          if (Xadd)  v += Xadd[(((size_t)b*64 + oc)*96 + yg)*96 + x];
          if (X0add) v += X0add[((size_t)oc*96 + yg)*96 + x];
          acc[mt][nt][r] = v;
        }
      }
  }
  if (MODE == 2){   // final iter: fused forward scan, fp32 NCHW stores
#pragma unroll
    for (int mt=0;mt<2;mt++)
#pragma unroll
      for (int nt=0;nt<3;nt++){
        const int x = wcol + nt*16 + n16;
#pragma unroll
        for (int r=0;r<4;r++){
          const int oc = h*32 + mt*16 + q*4 + r;
          size_t idx = (((size_t)b*64 + oc)*96 + yg)*96 + x;
          float prev = (b_i != 0.f) ? zb_prev[idx] : 0.f;
          zb_out[idx] = a_i*(b_i*prev + acc[mt][nt][r]);
        }
      }
    return;
  }

  __syncthreads();                        // all waves done with Bbc/Abc
  float* T = (float*)smem + w*1584;       // per-wave 48 x 33 fp32 transpose tile
#pragma unroll
  for (int mt2=0; mt2<2; mt2++)
#pragma unroll
    for (int nt=0;nt<3;nt++)
#pragma unroll
      for (int r=0;r<4;r++)
        T[(nt*16 + n16)*33 + mt2*16 + q*4 + r] = acc[mt2][nt][r];
  for (int f = lane; f < 384; f += 64){
    int px = f>>3, c4 = (f&7)*4;
    float vv[4];
#pragma unroll
    for (int k=0;k<4;k++) vv[k] = T[px*33 + c4 + k];
    int x = wcol + px;
    if (MODE == 0){
      float4 val = make_float4(vv[0], vv[1], vv[2], vv[3]);
      *(float4*)(outF + ((((size_t)b*96 + yg)*96 + x)*64 + h*32 + c4)) = val;
    } else {
      size_t off = ((size_t)(b*2 + h)*PY + (yg+1))*(size_t)PX*ICH
                 + (size_t)(x+1)*ICH + c4;
      uint2 pv = *(const uint2*)(yfq_prev + off);
      bf16* ph = (bf16*)&pv;
      union { uint2 v; unsigned short u[4]; } o;
#pragma unroll
      for (int k=0;k<4;k++){
        float yf = a_i*(b_i*(float)ph[k] + vv[k]);
        bf16 hh = (bf16)yf;
        o.u[k] = *(unsigned short*)&hh;
      }
      *(uint2*)(yfq_out + off) = o.v;
    }
  }
}

// ---------------------------------------------------------------------------
extern "C" void kernel_launch(void* const* d_in, const int* in_sizes, int n_in,
                              void* d_out, int out_size, void* d_ws, size_t ws_size,
                              hipStream_t stream) {
  const float* X  = (const float*)d_in[0];
  const float* K  = (const float*)d_in[1];
  const float* X0 = (const float*)d_in[2];

  float* out0  = (float*)d_out;
  float* zbase = out0 + LSTRIDE;

  char* ws = (char*)d_ws;
  float*  statacc = (float*)ws;                         // 24 steps x 1024 f (s,s2)
  bf16*   apf     = (bf16*)(ws + 98304);
  bf16*   apb     = apf + (size_t)NL*APK_L;
  bf16*   Zq      = apb + (size_t)NL*APK_L;             // 8*PL (doubles as Yfq)
  float*  dZf     = (float*)(Zq + (size_t)NL*PL);       // LSTRIDE f

  hipMemsetAsync(statacc, 0, 98304, stream);            // all 24 step slots
  hipMemsetAsync(Zq, 0, (size_t)NL*PL*2, stream);       // zero pads

  pack_weights<<<(NL*9*4096 + 255)/256, 256, 0, stream>>>(K, apf, apb);
  init_yf_t<<<dim3(HC, BB), 256, 0, stream>>>(X, X0, Zq);
  back_scan_q<<<PL/8/256, 256, 0, stream>>>(Zq);

  for (int it = 1; it <= 3; it++){
    for (int l = 0; l < NL; l++){
      float* accs = statacc + (size_t)((it-1)*NL + l)*1024;
      conv_mfma<0><<<dim3(48,8,2),256,0,stream>>>(
          Zq + (size_t)l*PL, nullptr, apf + (size_t)l*APK_L,
          dZf, accs, nullptr, nullptr, nullptr, nullptr,
          nullptr, nullptr, 0.f, 0.f);
      float ai = sqrtf((l+1.f)/(l+2.f)), bi = sqrtf((float)l/(float)(l+1));
      if (it < 3)
        conv_mfma<1><<<dim3(48,8,2),256,0,stream>>>(
            nullptr, dZf, apb + (size_t)l*APK_L,
            nullptr, accs, Zq + (size_t)l*PL, Zq + (size_t)(l>0?l-1:0)*PL,
            nullptr, nullptr,
            (l==NL-1)?X:nullptr, (l==0)?X0:nullptr, ai, bi);
      else
        conv_mfma<2><<<dim3(48,8,2),256,0,stream>>>(
            nullptr, dZf, apb + (size_t)l*APK_L,
            nullptr, accs, nullptr, nullptr,
            zbase + (size_t)l*LSTRIDE, zbase + (size_t)(l>0?l-1:0)*LSTRIDE,
            (l==NL-1)?X:nullptr, (l==0)?X0:nullptr, ai, bi);
    }
    if (it < 3) back_scan_q<<<PL/8/256,256,0,stream>>>(Zq);
    else        back_scan_final<<<LSTRIDE/256,256,0,stream>>>(zbase, out0);
  }
}

// Round 7
// 2709.420 us; speedup vs baseline: 1.0884x; 1.0884x over previous
//
#include <hip/hip_runtime.h>
#include <math.h>

// ---------------- problem constants ----------------
#define HC 96
#define WC 96
#define CCH 64
#define BB 8
#define NL 8
#define IMG (HC*WC)                 // 9216
#define LSTRIDE (BB*CCH*IMG)        // 4,718,592
#define EPS 1e-5f

// padded-chunked NHWC bf16 layout: [b][ch2][y:98][x:98][ic:32]
#define PY 98
#define PX 98
#define ICH 32
#define PLANE (PY*PX*ICH)           // 307,328
#define PL (BB*2*PLANE)             // 4,917,248 els per layer tensor
#define APK_L (2*9*2*64*32)         // 73,728 els per layer per direction

typedef __bf16 bf16;
typedef bf16 bf16x8 __attribute__((ext_vector_type(8)));
typedef float f32x4 __attribute__((ext_vector_type(4)));

__device__ __forceinline__ float a_of(int i){ return sqrtf((i+1.f)/(i+2.f)); }
__device__ __forceinline__ float b_of(int i){ return sqrtf((float)i/(float)(i+1)); }

// ---------------------------------------------------------------------------
// Split weights into hi/lo bf16 planes, frag-friendly layout:
// apX[l][ch][tap][rep][oc64][ic32]. fwd: K[l][oc][ic][tap]; bwd: K[l][ic][oc][8-tap].
__global__ void pack_weights(const float* __restrict__ K,
                             bf16* __restrict__ apf, bf16* __restrict__ apb){
  int idx = blockIdx.x*256 + threadIdx.x;          // NL*9*64*64
  if (idx >= NL*9*64*64) return;
  int ic = idx & 63, oc = (idx>>6) & 63;
  int tap = (idx>>12) % 9, l = idx/(4096*9);
  float wf = K[(((size_t)l*64 + oc)*64 + ic)*9 + tap];
  float wb = K[(((size_t)l*64 + ic)*64 + oc)*9 + (8-tap)];
  int ch = ic>>5, ic5 = ic&31;
  size_t base = (size_t)l*APK_L + ((size_t)((ch*9 + tap)*2)*64 + oc)*32 + ic5;
  bf16 fh = (bf16)wf;
  apf[base] = fh; apf[base + 64*32] = (bf16)(wf - (float)fh);
  bf16 bh = (bf16)wb;
  apb[base] = bh; apb[base + 64*32] = (bf16)(wb - (float)bh);
}

// ---------------------------------------------------------------------------
// Fix-iter 0 constant-folded: Yf closed form from X, X0; writes padded NHWC bf16.
__global__ __launch_bounds__(256) void init_yf_t(const float* __restrict__ X,
                                                 const float* __restrict__ X0,
                                                 bf16* __restrict__ yfq){
  __shared__ float LX[64][97];
  __shared__ float L0[64][97];
  int b = blockIdx.y, y = blockIdx.x;
  for (int i = threadIdx.x; i < 64*96; i += 256){
    int c = i/96, x = i%96;
    LX[c][x] = X[(((size_t)b*64 + c)*96 + y)*96 + x];
    L0[c][x] = X0[((size_t)c*96 + y)*96 + x];
  }
  __syncthreads();
  for (int j = threadIdx.x; j < 96*64; j += 256){
    int x = j>>6, c = j&63;
    float xv = LX[c][x], x0v = L0[c][x];
    size_t eoff = ((size_t)(b*2 + (c>>5))*PY + (y+1))*(size_t)PX*ICH
                + (size_t)(x+1)*ICH + (c&31);
    float yf = 0.f;
#pragma unroll
    for (int i = 0; i < NL; i++){
      float yv = (i==0 ? x0v : 0.f) + (i==NL-1 ? xv : 0.f);
      yf = a_of(i)*(b_of(i)*yf + yv);
      yfq[(size_t)i*PL + eoff] = (bf16)yf;
    }
  }
}

// ---------------------------------------------------------------------------
// Backward scan in place over padded bf16 Yf->Z (pads are 0 and map to 0).
__global__ __launch_bounds__(256) void back_scan_q(bf16* __restrict__ buf){
  size_t base = ((size_t)blockIdx.x*256 + threadIdx.x)*8;
  float c[8];
#pragma unroll
  for (int e=0;e<8;e++) c[e]=0.f;
#pragma unroll
  for (int l = NL-1; l >= 0; l--){
    float al = a_of(l);
    uint4 v = *(const uint4*)(buf + (size_t)l*PL + base);
    bf16* h = (bf16*)&v;
    uint4 o; bf16* ho = (bf16*)&o;
#pragma unroll
    for (int e=0;e<8;e++){
      float z = al*(al*c[e] + (float)h[e]);
      ho[e] = (bf16)z; c[e] = z;
    }
    *(uint4*)(buf + (size_t)l*PL + base) = o;
  }
}

// Final backward scan: fp32 NCHW in zbase (d_out), emits out0 = Z[7].
__global__ __launch_bounds__(256) void back_scan_final(float* __restrict__ zbase,
                                                       float* __restrict__ out0){
  int idx = blockIdx.x*256 + threadIdx.x;
  float c = 0.f;
#pragma unroll
  for (int i = NL-1; i >= 0; i--){
    float ai = a_of(i);
    float z = ai*(ai*c + zbase[(size_t)i*LSTRIDE + idx]);
    zbase[(size_t)i*LSTRIDE + idx] = z;
    if (i == NL-1) out0[idx] = z;
    c = z;
  }
}

// ---------------------------------------------------------------------------
// Normalize + leaky-relu + quantize to padded NHWC bf16 (pads untouched/zero).
// Finalizes instance-norm stats inline from the raw per-step (s, s2) slot
// (validated in R2).
__global__ __launch_bounds__(256) void norm_cvt(const float* __restrict__ dZf,
                                                const float* __restrict__ accstat,
                                                bf16* __restrict__ dzq){
  int i4 = blockIdx.x*256 + threadIdx.x;   // LSTRIDE/4
  size_t e = (size_t)i4*4;
  int oc = (int)(e & 63);
  size_t px = e >> 6;
  int x = (int)(px % 96); size_t t = px / 96;
  int y = (int)(t % 96);  int b = (int)(t / 96);
  const float* p = dZf + e;
  union { uint2 v; unsigned short u[4]; } o;
#pragma unroll
  for (int k=0;k<4;k++){
    int c = b*64 + oc + k;
    float s  = accstat[(size_t)c*2];
    float s2 = accstat[(size_t)c*2 + 1];
    float m = s*(1.f/IMG);
    float vv = s2*(1.f/IMG) - m*m;
    if (vv < 0.f) vv = 0.f;
    float rstd = rsqrtf(vv + EPS);
    float v = (p[k] - m)*rstd;
    v = (v >= 0.f) ? v : 0.2f*v;
    bf16 h = (bf16)v;
    o.u[k] = *(unsigned short*)&h;
  }
  size_t off = ((size_t)(b*2 + (oc>>5))*PY + (y+1))*(size_t)PX*ICH
             + (size_t)(x+1)*ICH + (oc&31);
  *(uint2*)(dzq + off) = o.v;
}

// ---------------------------------------------------------------------------
// MFMA implicit-GEMM 3x3 conv, pad=1, 2-pass split weights (Wh+Wl)*bf16(in).
// R7 = R1's conv VERBATIM (best measured: 2575 us total) plus ONE change:
// MODE 0's epilogue fuses the instance-norm partial stats (acc IS dZ;
// shfl_xor reduce over the 16-lane n16 group + per-wave atomics) — deletes
// the stats_partial and stat_fin dispatches. Inner loop untouched.
//  * oc split across blockIdx.z (2 half-blocks of 32 oc) -> grid 768 = 3*256.
//  * XOR bank-swizzle on BOTH LDS operand buffers (stage+read involution).
// Block: 32 oc x (2 rows x 96 cols); wave = 2 M-tiles x 3 N-tiles.
// MODE 0: -> dZf (NHWC fp32, via LDS transpose) + fused stats
// MODE 1: yv=-acc(+X/+X0); yf=a*(b*prev_q+yv) -> Yfq bf16 padded (transpose)
// MODE 2: same math fp32, direct NCHW stores to zbase (final iteration)
template<int MODE>
__global__ __launch_bounds__(256, 3) void conv_mfma(
    const bf16* __restrict__ inq, const bf16* __restrict__ apk,
    float* __restrict__ outF, float* __restrict__ accstat,
    bf16* __restrict__ yfq_out, const bf16* __restrict__ yfq_prev,
    float* __restrict__ zb_out, const float* __restrict__ zb_prev,
    const float* __restrict__ Xadd, const float* __restrict__ X0add,
    float a_i, float b_i)
{
  __shared__ __align__(16) char smem[25088 + 12288];
  char* Bbc = smem;                        // [4 rows][98 px][32 ic] bf16, swizzled
  char* Abc = smem + 25088;                // [3 taps][2 rep][32 oc][32 ic] bf16, swizzled

  const int rowg = blockIdx.x, b = blockIdx.y, h = blockIdx.z;  // h = oc half
  const int y0 = rowg*2;
  const int tid = threadIdx.x;
  const int w = tid>>6, lane = tid&63;
  const int n16 = lane&15, q = lane>>4;
  const int wr = w>>1, wcol = (w&1)*48;
  const int yg = y0 + wr;

  f32x4 acc[2][3];
#pragma unroll
  for (int a=0;a<2;a++)
#pragma unroll
    for (int c=0;c<3;c++){ f32x4 z = {0.f,0.f,0.f,0.f}; acc[a][c] = z; }

  for (int ch = 0; ch < 2; ch++){
    __syncthreads();
    { // stage 4 padded rows x 98 cols x 32 ic, swizzled 16B slots
      const uint4* src = (const uint4*)(inq + (size_t)(b*2 + ch)*PLANE
                                            + (size_t)y0*PX*ICH);
      for (int i = tid; i < 1568; i += 256){
        int r = i / 392, rem = i - r*392;        // 392 uint4 per padded row
        int px = rem >> 2, slot = rem & 3;
        int s = (px & 3) ^ ((px >> 2) & 3);
        *(uint4*)(Bbc + (size_t)r*6272 + (size_t)px*64 + ((slot ^ s)<<4)) = src[i];
      }
    }
    for (int tg = 0; tg < 3; tg++){       // tap row groups (ky = tg)
      __syncthreads();
      { // stage 3 taps x 2 reps x 32 oc (this block's half) x 32 ic, swizzled
        const uint4* srcA = (const uint4*)(apk + (size_t)ch*36864);
        for (int i = tid; i < 768; i += 256){
          int chunk = i >> 7, j = i & 127;       // chunk = tap_r*2+rep, 128 u4/chunk
          int tap_r = chunk >> 1, rep = chunk & 1;
          int oc = j >> 2, slot = j & 3;
          int s = (oc & 3) ^ ((oc >> 2) & 3);
          *(uint4*)(Abc + (size_t)chunk*2048 + (size_t)oc*64 + ((slot ^ s)<<4))
              = srcA[((size_t)((tg*3 + tap_r)*2 + rep))*256 + h*128 + j];
        }
      }
      __syncthreads();
#pragma unroll
      for (int tj = 0; tj < 3; tj++){     // kx = tj
        const int ky = tg, kx = tj;
        bf16x8 Ah[2], Al[2];
#pragma unroll
        for (int mt=0;mt<2;mt++){
          int oc32 = mt*16 + n16;
          int sA = (oc32 & 3) ^ ((oc32 >> 2) & 3);
          Ah[mt] = *(const bf16x8*)(Abc + (size_t)(tj*2 + 0)*2048 + (size_t)oc32*64 + ((q ^ sA)<<4));
          Al[mt] = *(const bf16x8*)(Abc + (size_t)(tj*2 + 1)*2048 + (size_t)oc32*64 + ((q ^ sA)<<4));
        }
        bf16x8 Bf[3];
#pragma unroll
        for (int nt=0;nt<3;nt++){
          int px = wcol + nt*16 + n16 + kx;
          int sB = (px & 3) ^ ((px >> 2) & 3);
          Bf[nt] = *(const bf16x8*)(Bbc + (size_t)(wr + ky)*6272 + (size_t)px*64 + ((q ^ sB)<<4));
        }
#pragma unroll
        for (int nt=0;nt<3;nt++)
#pragma unroll
          for (int mt=0;mt<2;mt++)
            acc[mt][nt] = __builtin_amdgcn_mfma_f32_16x16x32_bf16(Ah[mt], Bf[nt], acc[mt][nt], 0,0,0);
#pragma unroll
        for (int nt=0;nt<3;nt++)
#pragma unroll
          for (int mt=0;mt<2;mt++)
            acc[mt][nt] = __builtin_amdgcn_mfma_f32_16x16x32_bf16(Al[mt], Bf[nt], acc[mt][nt], 0,0,0);
      }
    }
  }

  // ---------------- epilogue ----------------
  if (MODE == 0){
    // fused instance-norm partial stats: acc IS dZ for this (oc, yg, 48 px)
    float sv[8], qv[8];
#pragma unroll
    for (int mt=0;mt<2;mt++)
#pragma unroll
      for (int r=0;r<4;r++){
        float a0 = acc[mt][0][r], a1 = acc[mt][1][r], a2 = acc[mt][2][r];
        sv[mt*4+r] = a0 + a1 + a2;
        qv[mt*4+r] = a0*a0 + a1*a1 + a2*a2;
      }
#pragma unroll
    for (int off=1; off<16; off<<=1)
#pragma unroll
      for (int k=0;k<8;k++){
        sv[k] += __shfl_xor(sv[k], off, 64);
        qv[k] += __shfl_xor(qv[k], off, 64);
      }
    if (n16 == 0){
#pragma unroll
      for (int k=0;k<8;k++){
        int oc = h*32 + (k>>2)*16 + q*4 + (k&3);
        atomicAdd(&accstat[((size_t)b*64 + oc)*2    ], sv[k]);
        atomicAdd(&accstat[((size_t)b*64 + oc)*2 + 1], qv[k]);
      }
    }
  }
  if (MODE >= 1){   // yv = -acc (+X at l=7) (+X0 at l=0); coalesced adds (x = lanes)
#pragma unroll
    for (int mt=0;mt<2;mt++)
#pragma unroll
      for (int nt=0;nt<3;nt++){
        const int x = wcol + nt*16 + n16;
#pragma unroll
        for (int r=0;r<4;r++){
          const int oc = h*32 + mt*16 + q*4 + r;
          float v = -acc[mt][nt][r];
          if (Xadd)  v += Xadd[(((size_t)b*64 + oc)*96 + yg)*96 + x];
          if (X0add) v += X0add[((size_t)oc*96 + yg)*96 + x];
          acc[mt][nt][r] = v;
        }
      }
  }
  if (MODE == 2){   // final iter: fused forward scan, fp32 NCHW stores
#pragma unroll
    for (int mt=0;mt<2;mt++)
#pragma unroll
      for (int nt=0;nt<3;nt++){
        const int x = wcol + nt*16 + n16;
#pragma unroll
        for (int r=0;r<4;r++){
          const int oc = h*32 + mt*16 + q*4 + r;
          size_t idx = (((size_t)b*64 + oc)*96 + yg)*96 + x;
          float prev = (b_i != 0.f) ? zb_prev[idx] : 0.f;
          zb_out[idx] = a_i*(b_i*prev + acc[mt][nt][r]);
        }
      }
    return;
  }

  __syncthreads();                        // all waves done with Bbc/Abc
  float* T = (float*)smem + w*1584;       // per-wave 48 x 33 fp32 transpose tile
#pragma unroll
  for (int mt2=0; mt2<2; mt2++)
#pragma unroll
    for (int nt=0;nt<3;nt++)
#pragma unroll
      for (int r=0;r<4;r++)
        T[(nt*16 + n16)*33 + mt2*16 + q*4 + r] = acc[mt2][nt][r];
  for (int f = lane; f < 384; f += 64){
    int px = f>>3, c4 = (f&7)*4;
    float vv[4];
#pragma unroll
    for (int k=0;k<4;k++) vv[k] = T[px*33 + c4 + k];
    int x = wcol + px;
    if (MODE == 0){
      float4 val = make_float4(vv[0], vv[1], vv[2], vv[3]);
      *(float4*)(outF + ((((size_t)b*96 + yg)*96 + x)*64 + h*32 + c4)) = val;
    } else {
      size_t off = ((size_t)(b*2 + h)*PY + (yg+1))*(size_t)PX*ICH
                 + (size_t)(x+1)*ICH + c4;
      uint2 pv = *(const uint2*)(yfq_prev + off);
      bf16* ph = (bf16*)&pv;
      union { uint2 v; unsigned short u[4]; } o;
#pragma unroll
      for (int k=0;k<4;k++){
        float yf = a_i*(b_i*(float)ph[k] + vv[k]);
        bf16 hh = (bf16)yf;
        o.u[k] = *(unsigned short*)&hh;
      }
      *(uint2*)(yfq_out + off) = o.v;
    }
  }
}

// ---------------------------------------------------------------------------
extern "C" void kernel_launch(void* const* d_in, const int* in_sizes, int n_in,
                              void* d_out, int out_size, void* d_ws, size_t ws_size,
                              hipStream_t stream) {
  const float* X  = (const float*)d_in[0];
  const float* K  = (const float*)d_in[1];
  const float* X0 = (const float*)d_in[2];

  float* out0  = (float*)d_out;
  float* zbase = out0 + LSTRIDE;

  char* ws = (char*)d_ws;
  float*  statacc = (float*)ws;                         // 24 steps x 1024 f (s,s2)
  bf16*   apf     = (bf16*)(ws + 98304);
  bf16*   apb     = apf + (size_t)NL*APK_L;
  bf16*   Zq      = apb + (size_t)NL*APK_L;             // 8*PL (doubles as Yfq)
  bf16*   dZq     = Zq + (size_t)NL*PL;                 // PL
  float*  dZf     = (float*)(dZq + PL);                 // LSTRIDE f

  hipMemsetAsync(statacc, 0, 98304, stream);            // all 24 step slots
  hipMemsetAsync(Zq, 0, (size_t)(NL+1)*PL*2, stream);   // zero pads (Zq + dZq)

  pack_weights<<<(NL*9*4096 + 255)/256, 256, 0, stream>>>(K, apf, apb);
  init_yf_t<<<dim3(HC, BB), 256, 0, stream>>>(X, X0, Zq);
  back_scan_q<<<PL/8/256, 256, 0, stream>>>(Zq);

  for (int it = 1; it <= 3; it++){
    for (int l = 0; l < NL; l++){
      float* accs = statacc + (size_t)((it-1)*NL + l)*1024;
      conv_mfma<0><<<dim3(48,8,2),256,0,stream>>>(
          Zq + (size_t)l*PL, apf + (size_t)l*APK_L,
          dZf, accs, nullptr, nullptr, nullptr, nullptr, nullptr, nullptr, 0.f, 0.f);
      norm_cvt<<<LSTRIDE/1024,256,0,stream>>>(dZf, accs, dZq);
      float ai = sqrtf((l+1.f)/(l+2.f)), bi = sqrtf((float)l/(float)(l+1));
      if (it < 3)
        conv_mfma<1><<<dim3(48,8,2),256,0,stream>>>(
            dZq, apb + (size_t)l*APK_L,
            nullptr, nullptr, Zq + (size_t)l*PL, Zq + (size_t)(l>0?l-1:0)*PL,
            nullptr, nullptr,
            (l==NL-1)?X:nullptr, (l==0)?X0:nullptr, ai, bi);
      else
        conv_mfma<2><<<dim3(48,8,2),256,0,stream>>>(
            dZq, apb + (size_t)l*APK_L,
            nullptr, nullptr, nullptr, nullptr,
            zbase + (size_t)l*LSTRIDE, zbase + (size_t)(l>0?l-1:0)*LSTRIDE,
            (l==NL-1)?X:nullptr, (l==0)?X0:nullptr, ai, bi);
    }
    if (it < 3) back_scan_q<<<PL/8/256,256,0,stream>>>(Zq);
    else        back_scan_final<<<LSTRIDE/256,256,0,stream>>>(zbase, out0);
  }
}

// Round 9
// 1772.992 us; speedup vs baseline: 1.6633x; 1.5282x over previous
//
#include <hip/hip_runtime.h>
#include <math.h>

// ---------------- problem constants ----------------
#define HC 96
#define WC 96
#define CCH 64
#define BB 8
#define NL 8
#define IMG (HC*WC)                 // 9216
#define LSTRIDE (BB*CCH*IMG)        // 4,718,592
#define EPS 1e-5f

// padded-chunked NHWC bf16 layout: [b][ch2][y:98][x:98][ic:32]
#define PY 98
#define PX 98
#define ICH 32
#define PLANE (PY*PX*ICH)           // 307,328
#define PL (BB*2*PLANE)             // 4,917,248 els per layer tensor
#define APK_L (2*9*2*64*32)         // 73,728 els per layer per direction

// padded stats layout: per (b,oc) a 128B slot; s at +0, s2 at +16 floats.
#define STAT_STRIDE 32              // floats per (b,oc) slot
#define STAT_SLOT (512*STAT_STRIDE) // floats per layer-step slot (64 KB)

typedef __bf16 bf16;
typedef bf16 bf16x8 __attribute__((ext_vector_type(8)));
typedef float f32x4 __attribute__((ext_vector_type(4)));

__device__ __forceinline__ float a_of(int i){ return sqrtf((i+1.f)/(i+2.f)); }
__device__ __forceinline__ float b_of(int i){ return sqrtf((float)i/(float)(i+1)); }

// ---------------------------------------------------------------------------
// Split weights into hi/lo bf16 planes, frag-friendly layout:
// apX[l][ch][tap][rep][oc64][ic32]. fwd: K[l][oc][ic][tap]; bwd: K[l][ic][oc][8-tap].
__global__ void pack_weights(const float* __restrict__ K,
                             bf16* __restrict__ apf, bf16* __restrict__ apb){
  int idx = blockIdx.x*256 + threadIdx.x;          // NL*9*64*64
  if (idx >= NL*9*64*64) return;
  int ic = idx & 63, oc = (idx>>6) & 63;
  int tap = (idx>>12) % 9, l = idx/(4096*9);
  float wf = K[(((size_t)l*64 + oc)*64 + ic)*9 + tap];
  float wb = K[(((size_t)l*64 + ic)*64 + oc)*9 + (8-tap)];
  int ch = ic>>5, ic5 = ic&31;
  size_t base = (size_t)l*APK_L + ((size_t)((ch*9 + tap)*2)*64 + oc)*32 + ic5;
  bf16 fh = (bf16)wf;
  apf[base] = fh; apf[base + 64*32] = (bf16)(wf - (float)fh);
  bf16 bh = (bf16)wb;
  apb[base] = bh; apb[base + 64*32] = (bf16)(wb - (float)bh);
}

// ---------------------------------------------------------------------------
// Fix-iter 0 constant-folded: Yf closed form from X, X0; writes padded NHWC bf16.
__global__ __launch_bounds__(256) void init_yf_t(const float* __restrict__ X,
                                                 const float* __restrict__ X0,
                                                 bf16* __restrict__ yfq){
  __shared__ float LX[64][97];
  __shared__ float L0[64][97];
  int b = blockIdx.y, y = blockIdx.x;
  for (int i = threadIdx.x; i < 64*96; i += 256){
    int c = i/96, x = i%96;
    LX[c][x] = X[(((size_t)b*64 + c)*96 + y)*96 + x];
    L0[c][x] = X0[((size_t)c*96 + y)*96 + x];
  }
  __syncthreads();
  for (int j = threadIdx.x; j < 96*64; j += 256){
    int x = j>>6, c = j&63;
    float xv = LX[c][x], x0v = L0[c][x];
    size_t eoff = ((size_t)(b*2 + (c>>5))*PY + (y+1))*(size_t)PX*ICH
                + (size_t)(x+1)*ICH + (c&31);
    float yf = 0.f;
#pragma unroll
    for (int i = 0; i < NL; i++){
      float yv = (i==0 ? x0v : 0.f) + (i==NL-1 ? xv : 0.f);
      yf = a_of(i)*(b_of(i)*yf + yv);
      yfq[(size_t)i*PL + eoff] = (bf16)yf;
    }
  }
}

// ---------------------------------------------------------------------------
// Backward scan in place over padded bf16 Yf->Z (pads are 0 and map to 0).
__global__ __launch_bounds__(256) void back_scan_q(bf16* __restrict__ buf){
  size_t base = ((size_t)blockIdx.x*256 + threadIdx.x)*8;
  float c[8];
#pragma unroll
  for (int e=0;e<8;e++) c[e]=0.f;
#pragma unroll
  for (int l = NL-1; l >= 0; l--){
    float al = a_of(l);
    uint4 v = *(const uint4*)(buf + (size_t)l*PL + base);
    bf16* h = (bf16*)&v;
    uint4 o; bf16* ho = (bf16*)&o;
#pragma unroll
    for (int e=0;e<8;e++){
      float z = al*(al*c[e] + (float)h[e]);
      ho[e] = (bf16)z; c[e] = z;
    }
    *(uint4*)(buf + (size_t)l*PL + base) = o;
  }
}

// Final backward scan: fp32 NCHW in zbase (d_out), emits out0 = Z[7].
__global__ __launch_bounds__(256) void back_scan_final(float* __restrict__ zbase,
                                                       float* __restrict__ out0){
  int idx = blockIdx.x*256 + threadIdx.x;
  float c = 0.f;
#pragma unroll
  for (int i = NL-1; i >= 0; i--){
    float ai = a_of(i);
    float z = ai*(ai*c + zbase[(size_t)i*LSTRIDE + idx]);
    zbase[(size_t)i*LSTRIDE + idx] = z;
    if (i == NL-1) out0[idx] = z;
    c = z;
  }
}

// ---------------------------------------------------------------------------
// Normalize + leaky-relu + quantize to padded NHWC bf16 (pads untouched/zero).
// Finalizes instance-norm stats inline from the raw per-step padded (s, s2)
// slot (stat_fin deleted; validated in R2).
__global__ __launch_bounds__(256) void norm_cvt(const float* __restrict__ dZf,
                                                const float* __restrict__ accstat,
                                                bf16* __restrict__ dzq){
  int i4 = blockIdx.x*256 + threadIdx.x;   // LSTRIDE/4
  size_t e = (size_t)i4*4;
  int oc = (int)(e & 63);
  size_t px = e >> 6;
  int x = (int)(px % 96); size_t t = px / 96;
  int y = (int)(t % 96);  int b = (int)(t / 96);
  const float* p = dZf + e;
  union { uint2 v; unsigned short u[4]; } o;
#pragma unroll
  for (int k=0;k<4;k++){
    int c = b*64 + oc + k;
    float s  = accstat[(size_t)c*STAT_STRIDE];
    float s2 = accstat[(size_t)c*STAT_STRIDE + 16];
    float m = s*(1.f/IMG);
    float vv = s2*(1.f/IMG) - m*m;
    if (vv < 0.f) vv = 0.f;
    float rstd = rsqrtf(vv + EPS);
    float v = (p[k] - m)*rstd;
    v = (v >= 0.f) ? v : 0.2f*v;
    bf16 h = (bf16)v;
    o.u[k] = *(unsigned short*)&h;
  }
  size_t off = ((size_t)(b*2 + (oc>>5))*PY + (y+1))*(size_t)PX*ICH
             + (size_t)(x+1)*ICH + (oc&31);
  *(uint2*)(dzq + off) = o.v;
}

// ---------------------------------------------------------------------------
// MFMA implicit-GEMM 3x3 conv, pad=1, 2-pass split weights (Wh+Wl)*bf16(in).
// R9 = R8 resubmitted byte-identical after a broker-level container failure
// (same pattern as R1->R2: infra error, not a kernel verdict).
// R8 = R1's conv verbatim; MODE 0's stats fusion REWORKED (R7's version cost
// ~+17us/dispatch — register pressure in the MFMA region + atomic line
// contention):
//  * stats accumulate from the epilogue's LDS transpose tile T, AFTER acc is
//    dead, piggybacked on the existing store loop (8 regs, post-MFMA only).
//  * per-wave shfl_xor totals -> 1KB LDS cross-wave combine -> ONE wave does
//    64 atomics/block into a PADDED layout (s and s2 each own a 64B line):
//    196k -> 49k atomics/dispatch, 1536 -> 96 atomics per cache line.
//  * oc split across blockIdx.z (2 half-blocks of 32 oc) -> grid 768 = 3*256.
//  * XOR bank-swizzle on BOTH LDS operand buffers (stage+read involution).
// Block: 32 oc x (2 rows x 96 cols); wave = 2 M-tiles x 3 N-tiles.
// MODE 0: -> dZf (NHWC fp32, via LDS transpose) + fused stats
// MODE 1: yv=-acc(+X/+X0); yf=a*(b*prev_q+yv) -> Yfq bf16 padded (transpose)
// MODE 2: same math fp32, direct NCHW stores to zbase (final iteration)
template<int MODE>
__global__ __launch_bounds__(256, 3) void conv_mfma(
    const bf16* __restrict__ inq, const bf16* __restrict__ apk,
    float* __restrict__ outF, float* __restrict__ accstat,
    bf16* __restrict__ yfq_out, const bf16* __restrict__ yfq_prev,
    float* __restrict__ zb_out, const float* __restrict__ zb_prev,
    const float* __restrict__ Xadd, const float* __restrict__ X0add,
    float a_i, float b_i)
{
  __shared__ __align__(16) char smem[25088 + 12288];
  char* Bbc = smem;                        // [4 rows][98 px][32 ic] bf16, swizzled
  char* Abc = smem + 25088;                // [3 taps][2 rep][32 oc][32 ic] bf16, swizzled
  __shared__ float sred[4][32];            // MODE 0 cross-wave stats combine
  __shared__ float qred[4][32];

  const int rowg = blockIdx.x, b = blockIdx.y, h = blockIdx.z;  // h = oc half
  const int y0 = rowg*2;
  const int tid = threadIdx.x;
  const int w = tid>>6, lane = tid&63;
  const int n16 = lane&15, q = lane>>4;
  const int wr = w>>1, wcol = (w&1)*48;
  const int yg = y0 + wr;

  f32x4 acc[2][3];
#pragma unroll
  for (int a=0;a<2;a++)
#pragma unroll
    for (int c=0;c<3;c++){ f32x4 z = {0.f,0.f,0.f,0.f}; acc[a][c] = z; }

  for (int ch = 0; ch < 2; ch++){
    __syncthreads();
    { // stage 4 padded rows x 98 cols x 32 ic, swizzled 16B slots
      const uint4* src = (const uint4*)(inq + (size_t)(b*2 + ch)*PLANE
                                            + (size_t)y0*PX*ICH);
      for (int i = tid; i < 1568; i += 256){
        int r = i / 392, rem = i - r*392;        // 392 uint4 per padded row
        int px = rem >> 2, slot = rem & 3;
        int s = (px & 3) ^ ((px >> 2) & 3);
        *(uint4*)(Bbc + (size_t)r*6272 + (size_t)px*64 + ((slot ^ s)<<4)) = src[i];
      }
    }
    for (int tg = 0; tg < 3; tg++){       // tap row groups (ky = tg)
      __syncthreads();
      { // stage 3 taps x 2 reps x 32 oc (this block's half) x 32 ic, swizzled
        const uint4* srcA = (const uint4*)(apk + (size_t)ch*36864);
        for (int i = tid; i < 768; i += 256){
          int chunk = i >> 7, j = i & 127;       // chunk = tap_r*2+rep, 128 u4/chunk
          int tap_r = chunk >> 1, rep = chunk & 1;
          int oc = j >> 2, slot = j & 3;
          int s = (oc & 3) ^ ((oc >> 2) & 3);
          *(uint4*)(Abc + (size_t)chunk*2048 + (size_t)oc*64 + ((slot ^ s)<<4))
              = srcA[((size_t)((tg*3 + tap_r)*2 + rep))*256 + h*128 + j];
        }
      }
      __syncthreads();
#pragma unroll
      for (int tj = 0; tj < 3; tj++){     // kx = tj
        const int ky = tg, kx = tj;
        bf16x8 Ah[2], Al[2];
#pragma unroll
        for (int mt=0;mt<2;mt++){
          int oc32 = mt*16 + n16;
          int sA = (oc32 & 3) ^ ((oc32 >> 2) & 3);
          Ah[mt] = *(const bf16x8*)(Abc + (size_t)(tj*2 + 0)*2048 + (size_t)oc32*64 + ((q ^ sA)<<4));
          Al[mt] = *(const bf16x8*)(Abc + (size_t)(tj*2 + 1)*2048 + (size_t)oc32*64 + ((q ^ sA)<<4));
        }
        bf16x8 Bf[3];
#pragma unroll
        for (int nt=0;nt<3;nt++){
          int px = wcol + nt*16 + n16 + kx;
          int sB = (px & 3) ^ ((px >> 2) & 3);
          Bf[nt] = *(const bf16x8*)(Bbc + (size_t)(wr + ky)*6272 + (size_t)px*64 + ((q ^ sB)<<4));
        }
#pragma unroll
        for (int nt=0;nt<3;nt++)
#pragma unroll
          for (int mt=0;mt<2;mt++)
            acc[mt][nt] = __builtin_amdgcn_mfma_f32_16x16x32_bf16(Ah[mt], Bf[nt], acc[mt][nt], 0,0,0);
#pragma unroll
        for (int nt=0;nt<3;nt++)
#pragma unroll
          for (int mt=0;mt<2;mt++)
            acc[mt][nt] = __builtin_amdgcn_mfma_f32_16x16x32_bf16(Al[mt], Bf[nt], acc[mt][nt], 0,0,0);
      }
    }
  }

  // ---------------- epilogue ----------------
  if (MODE >= 1){   // yv = -acc (+X at l=7) (+X0 at l=0); coalesced adds (x = lanes)
#pragma unroll
    for (int mt=0;mt<2;mt++)
#pragma unroll
      for (int nt=0;nt<3;nt++){
        const int x = wcol + nt*16 + n16;
#pragma unroll
        for (int r=0;r<4;r++){
          const int oc = h*32 + mt*16 + q*4 + r;
          float v = -acc[mt][nt][r];
          if (Xadd)  v += Xadd[(((size_t)b*64 + oc)*96 + yg)*96 + x];
          if (X0add) v += X0add[((size_t)oc*96 + yg)*96 + x];
          acc[mt][nt][r] = v;
        }
      }
  }
  if (MODE == 2){   // final iter: fused forward scan, fp32 NCHW stores
#pragma unroll
    for (int mt=0;mt<2;mt++)
#pragma unroll
      for (int nt=0;nt<3;nt++){
        const int x = wcol + nt*16 + n16;
#pragma unroll
        for (int r=0;r<4;r++){
          const int oc = h*32 + mt*16 + q*4 + r;
          size_t idx = (((size_t)b*64 + oc)*96 + yg)*96 + x;
          float prev = (b_i != 0.f) ? zb_prev[idx] : 0.f;
          zb_out[idx] = a_i*(b_i*prev + acc[mt][nt][r]);
        }
      }
    return;
  }

  __syncthreads();                        // all waves done with Bbc/Abc
  float* T = (float*)smem + w*1584;       // per-wave 48 x 33 fp32 transpose tile
#pragma unroll
  for (int mt2=0; mt2<2; mt2++)
#pragma unroll
    for (int nt=0;nt<3;nt++)
#pragma unroll
      for (int r=0;r<4;r++)
        T[(nt*16 + n16)*33 + mt2*16 + q*4 + r] = acc[mt2][nt][r];

  float s4[4] = {0.f,0.f,0.f,0.f};        // MODE 0: per-lane stats (acc now dead)
  float q4[4] = {0.f,0.f,0.f,0.f};
  for (int f = lane; f < 384; f += 64){
    int px = f>>3, c4 = (f&7)*4;
    float vv[4];
#pragma unroll
    for (int k=0;k<4;k++) vv[k] = T[px*33 + c4 + k];
    int x = wcol + px;
    if (MODE == 0){
      float4 val = make_float4(vv[0], vv[1], vv[2], vv[3]);
      *(float4*)(outF + ((((size_t)b*96 + yg)*96 + x)*64 + h*32 + c4)) = val;
#pragma unroll
      for (int k=0;k<4;k++){ s4[k] += vv[k]; q4[k] += vv[k]*vv[k]; }
    } else {
      size_t off = ((size_t)(b*2 + h)*PY + (yg+1))*(size_t)PX*ICH
                 + (size_t)(x+1)*ICH + c4;
      uint2 pv = *(const uint2*)(yfq_prev + off);
      bf16* ph = (bf16*)&pv;
      union { uint2 v; unsigned short u[4]; } o;
#pragma unroll
      for (int k=0;k<4;k++){
        float yf = a_i*(b_i*(float)ph[k] + vv[k]);
        bf16 hh = (bf16)yf;
        o.u[k] = *(unsigned short*)&hh;
      }
      *(uint2*)(yfq_out + off) = o.v;
    }
  }

  if (MODE == 0){
    // lanes sharing (lane&7) hold partials for the same 4 channels: xor 8/16/32
#pragma unroll
    for (int st = 8; st < 64; st <<= 1)
#pragma unroll
      for (int k=0;k<4;k++){
        s4[k] += __shfl_xor(s4[k], st, 64);
        q4[k] += __shfl_xor(q4[k], st, 64);
      }
    if (lane < 8){
#pragma unroll
      for (int k=0;k<4;k++){
        sred[w][lane*4 + k] = s4[k];
        qred[w][lane*4 + k] = q4[k];
      }
    }
    __syncthreads();
    if (tid < 32){
      float ss = sred[0][tid] + sred[1][tid] + sred[2][tid] + sred[3][tid];
      float qq = qred[0][tid] + qred[1][tid] + qred[2][tid] + qred[3][tid];
      size_t base = ((size_t)b*64 + h*32 + tid)*STAT_STRIDE;
      atomicAdd(&accstat[base], ss);
      atomicAdd(&accstat[base + 16], qq);
    }
  }
}

// ---------------------------------------------------------------------------
extern "C" void kernel_launch(void* const* d_in, const int* in_sizes, int n_in,
                              void* d_out, int out_size, void* d_ws, size_t ws_size,
                              hipStream_t stream) {
  const float* X  = (const float*)d_in[0];
  const float* K  = (const float*)d_in[1];
  const float* X0 = (const float*)d_in[2];

  float* out0  = (float*)d_out;
  float* zbase = out0 + LSTRIDE;

  char* ws = (char*)d_ws;
  float*  statacc = (float*)ws;                         // 24 steps x 64KB padded slots
  bf16*   apf     = (bf16*)(ws + 24*STAT_SLOT*4);
  bf16*   apb     = apf + (size_t)NL*APK_L;
  bf16*   Zq      = apb + (size_t)NL*APK_L;             // 8*PL (doubles as Yfq)
  bf16*   dZq     = Zq + (size_t)NL*PL;                 // PL
  float*  dZf     = (float*)(dZq + PL);                 // LSTRIDE f

  hipMemsetAsync(statacc, 0, 24*STAT_SLOT*4, stream);   // all 24 step slots
  hipMemsetAsync(Zq, 0, (size_t)(NL+1)*PL*2, stream);   // zero pads (Zq + dZq)

  pack_weights<<<(NL*9*4096 + 255)/256, 256, 0, stream>>>(K, apf, apb);
  init_yf_t<<<dim3(HC, BB), 256, 0, stream>>>(X, X0, Zq);
  back_scan_q<<<PL/8/256, 256, 0, stream>>>(Zq);

  for (int it = 1; it <= 3; it++){
    for (int l = 0; l < NL; l++){
      float* accs = statacc + (size_t)((it-1)*NL + l)*STAT_SLOT;
      conv_mfma<0><<<dim3(48,8,2),256,0,stream>>>(
          Zq + (size_t)l*PL, apf + (size_t)l*APK_L,
          dZf, accs, nullptr, nullptr, nullptr, nullptr, nullptr, nullptr, 0.f, 0.f);
      norm_cvt<<<LSTRIDE/1024,256,0,stream>>>(dZf, accs, dZq);
      float ai = sqrtf((l+1.f)/(l+2.f)), bi = sqrtf((float)l/(float)(l+1));
      if (it < 3)
        conv_mfma<1><<<dim3(48,8,2),256,0,stream>>>(
            dZq, apb + (size_t)l*APK_L,
            nullptr, nullptr, Zq + (size_t)l*PL, Zq + (size_t)(l>0?l-1:0)*PL,
            nullptr, nullptr,
            (l==NL-1)?X:nullptr, (l==0)?X0:nullptr, ai, bi);
      else
        conv_mfma<2><<<dim3(48,8,2),256,0,stream>>>(
            dZq, apb + (size_t)l*APK_L,
            nullptr, nullptr, nullptr, nullptr,
            zbase + (size_t)l*LSTRIDE, zbase + (size_t)(l>0?l-1:0)*LSTRIDE,
            (l==NL-1)?X:nullptr, (l==0)?X0:nullptr, ai, bi);
    }
    if (it < 3) back_scan_q<<<PL/8/256,256,0,stream>>>(Zq);
    else        back_scan_final<<<LSTRIDE/256,256,0,stream>>>(zbase, out0);
  }
}

// Round 10
// 1407.421 us; speedup vs baseline: 2.0953x; 1.2597x over previous
//
#include <hip/hip_runtime.h>
#include <math.h>

// ---------------- problem constants ----------------
#define HC 96
#define WC 96
#define CCH 64
#define BB 8
#define NL 8
#define IMG (HC*WC)                 // 9216
#define LSTRIDE (BB*CCH*IMG)        // 4,718,592
#define EPS 1e-5f

// padded-chunked NHWC bf16 layout: [b][ch2][y:98][x:98][ic:32]
#define PY 98
#define PX 98
#define ICH 32
#define PLANE (PY*PX*ICH)           // 307,328
#define PL (BB*2*PLANE)             // 4,917,248 els per layer tensor
#define APK_L (2*9*2*64*32)         // 73,728 els per layer per direction

// padded stats layout: per (b,oc) a 128B slot; s at +0, s2 at +16 floats.
#define STAT_STRIDE 32              // floats per (b,oc) slot
#define STAT_SLOT (512*STAT_STRIDE) // floats per layer-step slot (64 KB)

typedef __bf16 bf16;
typedef bf16 bf16x8 __attribute__((ext_vector_type(8)));
typedef float f32x4 __attribute__((ext_vector_type(4)));

__device__ __forceinline__ float a_of(int i){ return sqrtf((i+1.f)/(i+2.f)); }
__device__ __forceinline__ float b_of(int i){ return sqrtf((float)i/(float)(i+1)); }

// ---------------------------------------------------------------------------
// Split weights into hi/lo bf16 planes, frag-friendly layout:
// apX[l][ch][tap][rep][oc64][ic32]. fwd: K[l][oc][ic][tap]; bwd: K[l][ic][oc][8-tap].
__global__ void pack_weights(const float* __restrict__ K,
                             bf16* __restrict__ apf, bf16* __restrict__ apb){
  int idx = blockIdx.x*256 + threadIdx.x;          // NL*9*64*64
  if (idx >= NL*9*64*64) return;
  int ic = idx & 63, oc = (idx>>6) & 63;
  int tap = (idx>>12) % 9, l = idx/(4096*9);
  float wf = K[(((size_t)l*64 + oc)*64 + ic)*9 + tap];
  float wb = K[(((size_t)l*64 + ic)*64 + oc)*9 + (8-tap)];
  int ch = ic>>5, ic5 = ic&31;
  size_t base = (size_t)l*APK_L + ((size_t)((ch*9 + tap)*2)*64 + oc)*32 + ic5;
  bf16 fh = (bf16)wf;
  apf[base] = fh; apf[base + 64*32] = (bf16)(wf - (float)fh);
  bf16 bh = (bf16)wb;
  apb[base] = bh; apb[base + 64*32] = (bf16)(wb - (float)bh);
}

// ---------------------------------------------------------------------------
// Fix-iter 0 constant-folded: Yf closed form from X, X0; writes padded NHWC bf16.
__global__ __launch_bounds__(256) void init_yf_t(const float* __restrict__ X,
                                                 const float* __restrict__ X0,
                                                 bf16* __restrict__ yfq){
  __shared__ float LX[64][97];
  __shared__ float L0[64][97];
  int b = blockIdx.y, y = blockIdx.x;
  for (int i = threadIdx.x; i < 64*96; i += 256){
    int c = i/96, x = i%96;
    LX[c][x] = X[(((size_t)b*64 + c)*96 + y)*96 + x];
    L0[c][x] = X0[((size_t)c*96 + y)*96 + x];
  }
  __syncthreads();
  for (int j = threadIdx.x; j < 96*64; j += 256){
    int x = j>>6, c = j&63;
    float xv = LX[c][x], x0v = L0[c][x];
    size_t eoff = ((size_t)(b*2 + (c>>5))*PY + (y+1))*(size_t)PX*ICH
                + (size_t)(x+1)*ICH + (c&31);
    float yf = 0.f;
#pragma unroll
    for (int i = 0; i < NL; i++){
      float yv = (i==0 ? x0v : 0.f) + (i==NL-1 ? xv : 0.f);
      yf = a_of(i)*(b_of(i)*yf + yv);
      yfq[(size_t)i*PL + eoff] = (bf16)yf;
    }
  }
}

// ---------------------------------------------------------------------------
// Backward scan in place over padded bf16 Yf->Z (pads are 0 and map to 0).
__global__ __launch_bounds__(256) void back_scan_q(bf16* __restrict__ buf){
  size_t base = ((size_t)blockIdx.x*256 + threadIdx.x)*8;
  float c[8];
#pragma unroll
  for (int e=0;e<8;e++) c[e]=0.f;
#pragma unroll
  for (int l = NL-1; l >= 0; l--){
    float al = a_of(l);
    uint4 v = *(const uint4*)(buf + (size_t)l*PL + base);
    bf16* h = (bf16*)&v;
    uint4 o; bf16* ho = (bf16*)&o;
#pragma unroll
    for (int e=0;e<8;e++){
      float z = al*(al*c[e] + (float)h[e]);
      ho[e] = (bf16)z; c[e] = z;
    }
    *(uint4*)(buf + (size_t)l*PL + base) = o;
  }
}

// Final backward scan: fp32 NCHW in zbase (d_out), emits out0 = Z[7].
__global__ __launch_bounds__(256) void back_scan_final(float* __restrict__ zbase,
                                                       float* __restrict__ out0){
  int idx = blockIdx.x*256 + threadIdx.x;
  float c = 0.f;
#pragma unroll
  for (int i = NL-1; i >= 0; i--){
    float ai = a_of(i);
    float z = ai*(ai*c + zbase[(size_t)i*LSTRIDE + idx]);
    zbase[(size_t)i*LSTRIDE + idx] = z;
    if (i == NL-1) out0[idx] = z;
    c = z;
  }
}

// ---------------------------------------------------------------------------
// MFMA implicit-GEMM 3x3 conv, pad=1, 2-pass split weights (Wh+Wl)*bf16(in).
// R10 = R9 (1773 us) + ONE isolated change: norm_cvt folded into conv<1/2>'s
// B staging (numerically validated in R5; R5's perf regression was its
// rep-split A staging, not this). conv<1/2> stage B from fp32 dZf applying
// normalize + leaky-relu + bf16 quantize inline; per-channel (m,rstd)
// finalized once into 512B LDS at kernel start from the padded stats slot.
// norm_cvt kernel and dZq tensor deleted (24 fewer dispatches).
// R9's proven pieces, untouched:
//  * R1 conv inner loop verbatim; XOR bank-swizzle on both LDS buffers.
//  * MODE 0 fused stats from epilogue transpose tile T (post-acc), per-wave
//    shfl_xor + 1KB LDS combine + 64 padded-line atomics/block.
//  * oc split across blockIdx.z -> grid 768 = 3*256, 3 blocks/CU.
// Block: 32 oc x (2 rows x 96 cols); wave = 2 M-tiles x 3 N-tiles.
// MODE 0: in=Zq[l] -> dZf (NHWC fp32, LDS transpose) + fused stats
// MODE 1: in=dZf+stats; yv=-acc(+X/+X0); yf=a*(b*prev_q+yv) -> Yfq bf16 padded
// MODE 2: in=dZf+stats; same math fp32, direct NCHW stores to zbase (final it)
template<int MODE>
__global__ __launch_bounds__(256, 3) void conv_mfma(
    const bf16* __restrict__ inq, const float* __restrict__ dzf_in,
    const bf16* __restrict__ apk,
    float* __restrict__ outF, float* __restrict__ accstat,
    bf16* __restrict__ yfq_out, const bf16* __restrict__ yfq_prev,
    float* __restrict__ zb_out, const float* __restrict__ zb_prev,
    const float* __restrict__ Xadd, const float* __restrict__ X0add,
    float a_i, float b_i)
{
  __shared__ __align__(16) char smem[25088 + 12288];
  char* Bbc = smem;                        // [4 rows][98 px][32 ic] bf16, swizzled
  char* Abc = smem + 25088;                // [3 taps][2 rep][32 oc][32 ic] bf16, swizzled
  __shared__ float sred[4][32];            // MODE 0 cross-wave stats combine
  __shared__ float qred[4][32];
  __shared__ float2 stat_s[64];            // MODE>=1 per-channel (m, rstd)

  const int rowg = blockIdx.x, b = blockIdx.y, h = blockIdx.z;  // h = oc half
  const int y0 = rowg*2;
  const int tid = threadIdx.x;
  const int w = tid>>6, lane = tid&63;
  const int n16 = lane&15, q = lane>>4;
  const int wr = w>>1, wcol = (w&1)*48;
  const int yg = y0 + wr;

  if (MODE >= 1){   // finalize instance-norm stats for this b (padded slot)
    if (tid < 64){
      float s  = accstat[((size_t)b*64 + tid)*STAT_STRIDE];
      float s2 = accstat[((size_t)b*64 + tid)*STAT_STRIDE + 16];
      float m = s*(1.f/IMG);
      float vv = s2*(1.f/IMG) - m*m;
      if (vv < 0.f) vv = 0.f;
      stat_s[tid] = make_float2(m, rsqrtf(vv + EPS));
    }
    __syncthreads();
  }

  f32x4 acc[2][3];
#pragma unroll
  for (int a=0;a<2;a++)
#pragma unroll
    for (int c=0;c<3;c++){ f32x4 z = {0.f,0.f,0.f,0.f}; acc[a][c] = z; }

  for (int ch = 0; ch < 2; ch++){
    __syncthreads();
    if (MODE == 0){
      // stage 4 padded rows x 98 cols x 32 ic, swizzled 16B slots (raw bf16)
      const uint4* src = (const uint4*)(inq + (size_t)(b*2 + ch)*PLANE
                                            + (size_t)y0*PX*ICH);
      for (int i = tid; i < 1568; i += 256){
        int r = i / 392, rem = i - r*392;        // 392 uint4 per padded row
        int px = rem >> 2, slot = rem & 3;
        int s = (px & 3) ^ ((px >> 2) & 3);
        *(uint4*)(Bbc + (size_t)r*6272 + (size_t)px*64 + ((slot ^ s)<<4)) = src[i];
      }
    } else {
      // stage from fp32 dZf with fused normalize + leaky-relu + quantize
      for (int i = tid; i < 1568; i += 256){
        int r = i / 392, rem = i - r*392;
        int px = rem >> 2, slot = rem & 3;
        int s = (px & 3) ^ ((px >> 2) & 3);
        int y = y0 - 1 + r;
        int x = px - 1;
        union { uint4 v; unsigned short u[8]; } o;
        if (y >= 0 && y < 96 && x >= 0 && x < 96){
          const float* sp = dzf_in + (((size_t)(b*96 + y)*96 + x)*64 + ch*32 + slot*8);
          f32x4 v0 = *(const f32x4*)sp;
          f32x4 v1 = *(const f32x4*)(sp + 4);
#pragma unroll
          for (int k=0;k<8;k++){
            float2 mr = stat_s[ch*32 + slot*8 + k];
            float f = (k < 4) ? v0[k] : v1[k-4];
            float v = (f - mr.x)*mr.y;
            v = (v >= 0.f) ? v : 0.2f*v;
            bf16 hh = (bf16)v;
            o.u[k] = *(unsigned short*)&hh;
          }
        } else {
          o.v = make_uint4(0u,0u,0u,0u);
        }
        *(uint4*)(Bbc + (size_t)r*6272 + (size_t)px*64 + ((slot ^ s)<<4)) = o.v;
      }
    }
    for (int tg = 0; tg < 3; tg++){       // tap row groups (ky = tg)
      __syncthreads();
      { // stage 3 taps x 2 reps x 32 oc (this block's half) x 32 ic, swizzled
        const uint4* srcA = (const uint4*)(apk + (size_t)ch*36864);
        for (int i = tid; i < 768; i += 256){
          int chunk = i >> 7, j = i & 127;       // chunk = tap_r*2+rep, 128 u4/chunk
          int tap_r = chunk >> 1, rep = chunk & 1;
          int oc = j >> 2, slot = j & 3;
          int s = (oc & 3) ^ ((oc >> 2) & 3);
          *(uint4*)(Abc + (size_t)chunk*2048 + (size_t)oc*64 + ((slot ^ s)<<4))
              = srcA[((size_t)((tg*3 + tap_r)*2 + rep))*256 + h*128 + j];
        }
      }
      __syncthreads();
#pragma unroll
      for (int tj = 0; tj < 3; tj++){     // kx = tj
        const int ky = tg, kx = tj;
        bf16x8 Ah[2], Al[2];
#pragma unroll
        for (int mt=0;mt<2;mt++){
          int oc32 = mt*16 + n16;
          int sA = (oc32 & 3) ^ ((oc32 >> 2) & 3);
          Ah[mt] = *(const bf16x8*)(Abc + (size_t)(tj*2 + 0)*2048 + (size_t)oc32*64 + ((q ^ sA)<<4));
          Al[mt] = *(const bf16x8*)(Abc + (size_t)(tj*2 + 1)*2048 + (size_t)oc32*64 + ((q ^ sA)<<4));
        }
        bf16x8 Bf[3];
#pragma unroll
        for (int nt=0;nt<3;nt++){
          int px = wcol + nt*16 + n16 + kx;
          int sB = (px & 3) ^ ((px >> 2) & 3);
          Bf[nt] = *(const bf16x8*)(Bbc + (size_t)(wr + ky)*6272 + (size_t)px*64 + ((q ^ sB)<<4));
        }
#pragma unroll
        for (int nt=0;nt<3;nt++)
#pragma unroll
          for (int mt=0;mt<2;mt++)
            acc[mt][nt] = __builtin_amdgcn_mfma_f32_16x16x32_bf16(Ah[mt], Bf[nt], acc[mt][nt], 0,0,0);
#pragma unroll
        for (int nt=0;nt<3;nt++)
#pragma unroll
          for (int mt=0;mt<2;mt++)
            acc[mt][nt] = __builtin_amdgcn_mfma_f32_16x16x32_bf16(Al[mt], Bf[nt], acc[mt][nt], 0,0,0);
      }
    }
  }

  // ---------------- epilogue ----------------
  if (MODE >= 1){   // yv = -acc (+X at l=7) (+X0 at l=0); coalesced adds (x = lanes)
#pragma unroll
    for (int mt=0;mt<2;mt++)
#pragma unroll
      for (int nt=0;nt<3;nt++){
        const int x = wcol + nt*16 + n16;
#pragma unroll
        for (int r=0;r<4;r++){
          const int oc = h*32 + mt*16 + q*4 + r;
          float v = -acc[mt][nt][r];
          if (Xadd)  v += Xadd[(((size_t)b*64 + oc)*96 + yg)*96 + x];
          if (X0add) v += X0add[((size_t)oc*96 + yg)*96 + x];
          acc[mt][nt][r] = v;
        }
      }
  }
  if (MODE == 2){   // final iter: fused forward scan, fp32 NCHW stores
#pragma unroll
    for (int mt=0;mt<2;mt++)
#pragma unroll
      for (int nt=0;nt<3;nt++){
        const int x = wcol + nt*16 + n16;
#pragma unroll
        for (int r=0;r<4;r++){
          const int oc = h*32 + mt*16 + q*4 + r;
          size_t idx = (((size_t)b*64 + oc)*96 + yg)*96 + x;
          float prev = (b_i != 0.f) ? zb_prev[idx] : 0.f;
          zb_out[idx] = a_i*(b_i*prev + acc[mt][nt][r]);
        }
      }
    return;
  }

  __syncthreads();                        // all waves done with Bbc/Abc
  float* T = (float*)smem + w*1584;       // per-wave 48 x 33 fp32 transpose tile
#pragma unroll
  for (int mt2=0; mt2<2; mt2++)
#pragma unroll
    for (int nt=0;nt<3;nt++)
#pragma unroll
      for (int r=0;r<4;r++)
        T[(nt*16 + n16)*33 + mt2*16 + q*4 + r] = acc[mt2][nt][r];

  float s4[4] = {0.f,0.f,0.f,0.f};        // MODE 0: per-lane stats (acc now dead)
  float q4[4] = {0.f,0.f,0.f,0.f};
  for (int f = lane; f < 384; f += 64){
    int px = f>>3, c4 = (f&7)*4;
    float vv[4];
#pragma unroll
    for (int k=0;k<4;k++) vv[k] = T[px*33 + c4 + k];
    int x = wcol + px;
    if (MODE == 0){
      float4 val = make_float4(vv[0], vv[1], vv[2], vv[3]);
      *(float4*)(outF + ((((size_t)b*96 + yg)*96 + x)*64 + h*32 + c4)) = val;
#pragma unroll
      for (int k=0;k<4;k++){ s4[k] += vv[k]; q4[k] += vv[k]*vv[k]; }
    } else {
      size_t off = ((size_t)(b*2 + h)*PY + (yg+1))*(size_t)PX*ICH
                 + (size_t)(x+1)*ICH + c4;
      uint2 pv = *(const uint2*)(yfq_prev + off);
      bf16* ph = (bf16*)&pv;
      union { uint2 v; unsigned short u[4]; } o;
#pragma unroll
      for (int k=0;k<4;k++){
        float yf = a_i*(b_i*(float)ph[k] + vv[k]);
        bf16 hh = (bf16)yf;
        o.u[k] = *(unsigned short*)&hh;
      }
      *(uint2*)(yfq_out + off) = o.v;
    }
  }

  if (MODE == 0){
    // lanes sharing (lane&7) hold partials for the same 4 channels: xor 8/16/32
#pragma unroll
    for (int st = 8; st < 64; st <<= 1)
#pragma unroll
      for (int k=0;k<4;k++){
        s4[k] += __shfl_xor(s4[k], st, 64);
        q4[k] += __shfl_xor(q4[k], st, 64);
      }
    if (lane < 8){
#pragma unroll
      for (int k=0;k<4;k++){
        sred[w][lane*4 + k] = s4[k];
        qred[w][lane*4 + k] = q4[k];
      }
    }
    __syncthreads();
    if (tid < 32){
      float ss = sred[0][tid] + sred[1][tid] + sred[2][tid] + sred[3][tid];
      float qq = qred[0][tid] + qred[1][tid] + qred[2][tid] + qred[3][tid];
      size_t base = ((size_t)b*64 + h*32 + tid)*STAT_STRIDE;
      atomicAdd(&accstat[base], ss);
      atomicAdd(&accstat[base + 16], qq);
    }
  }
}

// ---------------------------------------------------------------------------
extern "C" void kernel_launch(void* const* d_in, const int* in_sizes, int n_in,
                              void* d_out, int out_size, void* d_ws, size_t ws_size,
                              hipStream_t stream) {
  const float* X  = (const float*)d_in[0];
  const float* K  = (const float*)d_in[1];
  const float* X0 = (const float*)d_in[2];

  float* out0  = (float*)d_out;
  float* zbase = out0 + LSTRIDE;

  char* ws = (char*)d_ws;
  float*  statacc = (float*)ws;                         // 24 steps x 64KB padded slots
  bf16*   apf     = (bf16*)(ws + 24*STAT_SLOT*4);
  bf16*   apb     = apf + (size_t)NL*APK_L;
  bf16*   Zq      = apb + (size_t)NL*APK_L;             // 8*PL (doubles as Yfq)
  float*  dZf     = (float*)(Zq + (size_t)NL*PL);       // LSTRIDE f

  hipMemsetAsync(statacc, 0, 24*STAT_SLOT*4, stream);   // all 24 step slots
  hipMemsetAsync(Zq, 0, (size_t)NL*PL*2, stream);       // zero pads

  pack_weights<<<(NL*9*4096 + 255)/256, 256, 0, stream>>>(K, apf, apb);
  init_yf_t<<<dim3(HC, BB), 256, 0, stream>>>(X, X0, Zq);
  back_scan_q<<<PL/8/256, 256, 0, stream>>>(Zq);

  for (int it = 1; it <= 3; it++){
    for (int l = 0; l < NL; l++){
      float* accs = statacc + (size_t)((it-1)*NL + l)*STAT_SLOT;
      conv_mfma<0><<<dim3(48,8,2),256,0,stream>>>(
          Zq + (size_t)l*PL, nullptr, apf + (size_t)l*APK_L,
          dZf, accs, nullptr, nullptr, nullptr, nullptr,
          nullptr, nullptr, 0.f, 0.f);
      float ai = sqrtf((l+1.f)/(l+2.f)), bi = sqrtf((float)l/(float)(l+1));
      if (it < 3)
        conv_mfma<1><<<dim3(48,8,2),256,0,stream>>>(
            nullptr, dZf, apb + (size_t)l*APK_L,
            nullptr, accs, Zq + (size_t)l*PL, Zq + (size_t)(l>0?l-1:0)*PL,
            nullptr, nullptr,
            (l==NL-1)?X:nullptr, (l==0)?X0:nullptr, ai, bi);
      else
        conv_mfma<2><<<dim3(48,8,2),256,0,stream>>>(
            nullptr, dZf, apb + (size_t)l*APK_L,
            nullptr, accs, nullptr, nullptr,
            zbase + (size_t)l*LSTRIDE, zbase + (size_t)(l>0?l-1:0)*LSTRIDE,
            (l==NL-1)?X:nullptr, (l==0)?X0:nullptr, ai, bi);
    }
    if (it < 3) back_scan_q<<<PL/8/256,256,0,stream>>>(Zq);
    else        back_scan_final<<<LSTRIDE/256,256,0,stream>>>(zbase, out0);
  }
}

// Round 11
// 1369.639 us; speedup vs baseline: 2.1531x; 1.0276x over previous
//
#include <hip/hip_runtime.h>
#include <math.h>

// ---------------- problem constants ----------------
#define HC 96
#define WC 96
#define CCH 64
#define BB 8
#define NL 8
#define IMG (HC*WC)                 // 9216
#define LSTRIDE (BB*CCH*IMG)        // 4,718,592
#define EPS 1e-5f

// padded-chunked NHWC bf16 layout: [b][ch2][y:98][x:98][ic:32]
#define PY 98
#define PX 98
#define ICH 32
#define PLANE (PY*PX*ICH)           // 307,328
#define PL (BB*2*PLANE)             // 4,917,248 els per layer tensor
#define APK_L (2*9*2*64*32)         // 73,728 els per layer per direction

// padded stats layout: per (b,oc) a 128B slot; s at +0, s2 at +16 floats.
#define STAT_STRIDE 32              // floats per (b,oc) slot
#define STAT_SLOT (512*STAT_STRIDE) // floats per layer-step slot (64 KB)

typedef __bf16 bf16;
typedef bf16 bf16x8 __attribute__((ext_vector_type(8)));
typedef float f32x4 __attribute__((ext_vector_type(4)));

__device__ __forceinline__ float a_of(int i){ return sqrtf((i+1.f)/(i+2.f)); }
__device__ __forceinline__ float b_of(int i){ return sqrtf((float)i/(float)(i+1)); }

// ---------------------------------------------------------------------------
// Split weights into hi/lo bf16 planes, frag-friendly layout:
// apX[l][ch][tap][rep][oc64][ic32]. fwd: K[l][oc][ic][tap]; bwd: K[l][ic][oc][8-tap].
__global__ void pack_weights(const float* __restrict__ K,
                             bf16* __restrict__ apf, bf16* __restrict__ apb){
  int idx = blockIdx.x*256 + threadIdx.x;          // NL*9*64*64
  if (idx >= NL*9*64*64) return;
  int ic = idx & 63, oc = (idx>>6) & 63;
  int tap = (idx>>12) % 9, l = idx/(4096*9);
  float wf = K[(((size_t)l*64 + oc)*64 + ic)*9 + tap];
  float wb = K[(((size_t)l*64 + ic)*64 + oc)*9 + (8-tap)];
  int ch = ic>>5, ic5 = ic&31;
  size_t base = (size_t)l*APK_L + ((size_t)((ch*9 + tap)*2)*64 + oc)*32 + ic5;
  bf16 fh = (bf16)wf;
  apf[base] = fh; apf[base + 64*32] = (bf16)(wf - (float)fh);
  bf16 bh = (bf16)wb;
  apb[base] = bh; apb[base + 64*32] = (bf16)(wb - (float)bh);
}

// ---------------------------------------------------------------------------
// Fix-iter 0 constant-folded: Yf closed form from X, X0; writes padded NHWC bf16.
__global__ __launch_bounds__(256) void init_yf_t(const float* __restrict__ X,
                                                 const float* __restrict__ X0,
                                                 bf16* __restrict__ yfq){
  __shared__ float LX[64][97];
  __shared__ float L0[64][97];
  int b = blockIdx.y, y = blockIdx.x;
  for (int i = threadIdx.x; i < 64*96; i += 256){
    int c = i/96, x = i%96;
    LX[c][x] = X[(((size_t)b*64 + c)*96 + y)*96 + x];
    L0[c][x] = X0[((size_t)c*96 + y)*96 + x];
  }
  __syncthreads();
  for (int j = threadIdx.x; j < 96*64; j += 256){
    int x = j>>6, c = j&63;
    float xv = LX[c][x], x0v = L0[c][x];
    size_t eoff = ((size_t)(b*2 + (c>>5))*PY + (y+1))*(size_t)PX*ICH
                + (size_t)(x+1)*ICH + (c&31);
    float yf = 0.f;
#pragma unroll
    for (int i = 0; i < NL; i++){
      float yv = (i==0 ? x0v : 0.f) + (i==NL-1 ? xv : 0.f);
      yf = a_of(i)*(b_of(i)*yf + yv);
      yfq[(size_t)i*PL + eoff] = (bf16)yf;
    }
  }
}

// ---------------------------------------------------------------------------
// Backward scan in place over padded bf16 Yf->Z (pads are 0 and map to 0).
__global__ __launch_bounds__(256) void back_scan_q(bf16* __restrict__ buf){
  size_t base = ((size_t)blockIdx.x*256 + threadIdx.x)*8;
  float c[8];
#pragma unroll
  for (int e=0;e<8;e++) c[e]=0.f;
#pragma unroll
  for (int l = NL-1; l >= 0; l--){
    float al = a_of(l);
    uint4 v = *(const uint4*)(buf + (size_t)l*PL + base);
    bf16* h = (bf16*)&v;
    uint4 o; bf16* ho = (bf16*)&o;
#pragma unroll
    for (int e=0;e<8;e++){
      float z = al*(al*c[e] + (float)h[e]);
      ho[e] = (bf16)z; c[e] = z;
    }
    *(uint4*)(buf + (size_t)l*PL + base) = o;
  }
}

// Final backward scan: fp32 NCHW in zbase (d_out), emits out0 = Z[7].
__global__ __launch_bounds__(256) void back_scan_final(float* __restrict__ zbase,
                                                       float* __restrict__ out0){
  int idx = blockIdx.x*256 + threadIdx.x;
  float c = 0.f;
#pragma unroll
  for (int i = NL-1; i >= 0; i--){
    float ai = a_of(i);
    float z = ai*(ai*c + zbase[(size_t)i*LSTRIDE + idx]);
    zbase[(size_t)i*LSTRIDE + idx] = z;
    if (i == NL-1) out0[idx] = z;
    c = z;
  }
}

// ---------------------------------------------------------------------------
// MFMA implicit-GEMM 3x3 conv, pad=1, 2-pass split weights (Wh+Wl)*bf16(in).
// R11 = R10 (1407 us) + ONE isolated change: the dZ intermediate becomes
// padded-layout bf16 (dZq) instead of NHWC fp32 (dZf):
//  * MODE 0 epilogue stores raw (pre-norm) bf16 dZ via the proven MODE-1
//    store addressing; stats still computed from fp32 acc (exact).
//  * MODE 1/2 staging: contiguous uint4 reads of dZq (same index math as
//    MODE 0 raw staging), per-uint4 pad test (uniform: a uint4 = 8 channels
//    of one pixel), normalize+lrelu+requantize in flight.
//  Saves ~29 MB HBM per layer-step (conv<0> write halved, conv<1> double
//  read halved); one extra bf16 rounding pre-norm (stats remain exact).
// R10's proven pieces, untouched: R1 conv inner loop + XOR swizzle; MODE 0
// fused stats (post-acc, padded atomic lines); grid 768 = 3*256.
// Block: 32 oc x (2 rows x 96 cols); wave = 2 M-tiles x 3 N-tiles.
// MODE 0: in=Zq[l] -> dZq (padded bf16, LDS transpose) + fused stats
// MODE 1: in=dZq+stats; yv=-acc(+X/+X0); yf=a*(b*prev_q+yv) -> Yfq bf16 padded
// MODE 2: in=dZq+stats; same math fp32, direct NCHW stores to zbase (final it)
template<int MODE>
__global__ __launch_bounds__(256, 3) void conv_mfma(
    const bf16* __restrict__ inq, const bf16* __restrict__ dzq_in,
    const bf16* __restrict__ apk,
    bf16* __restrict__ dzq_out, float* __restrict__ accstat,
    bf16* __restrict__ yfq_out, const bf16* __restrict__ yfq_prev,
    float* __restrict__ zb_out, const float* __restrict__ zb_prev,
    const float* __restrict__ Xadd, const float* __restrict__ X0add,
    float a_i, float b_i)
{
  __shared__ __align__(16) char smem[25088 + 12288];
  char* Bbc = smem;                        // [4 rows][98 px][32 ic] bf16, swizzled
  char* Abc = smem + 25088;                // [3 taps][2 rep][32 oc][32 ic] bf16, swizzled
  __shared__ float sred[4][32];            // MODE 0 cross-wave stats combine
  __shared__ float qred[4][32];
  __shared__ float2 stat_s[64];            // MODE>=1 per-channel (m, rstd)

  const int rowg = blockIdx.x, b = blockIdx.y, h = blockIdx.z;  // h = oc half
  const int y0 = rowg*2;
  const int tid = threadIdx.x;
  const int w = tid>>6, lane = tid&63;
  const int n16 = lane&15, q = lane>>4;
  const int wr = w>>1, wcol = (w&1)*48;
  const int yg = y0 + wr;

  if (MODE >= 1){   // finalize instance-norm stats for this b (padded slot)
    if (tid < 64){
      float s  = accstat[((size_t)b*64 + tid)*STAT_STRIDE];
      float s2 = accstat[((size_t)b*64 + tid)*STAT_STRIDE + 16];
      float m = s*(1.f/IMG);
      float vv = s2*(1.f/IMG) - m*m;
      if (vv < 0.f) vv = 0.f;
      stat_s[tid] = make_float2(m, rsqrtf(vv + EPS));
    }
    __syncthreads();
  }

  f32x4 acc[2][3];
#pragma unroll
  for (int a=0;a<2;a++)
#pragma unroll
    for (int c=0;c<3;c++){ f32x4 z = {0.f,0.f,0.f,0.f}; acc[a][c] = z; }

  for (int ch = 0; ch < 2; ch++){
    __syncthreads();
    if (MODE == 0){
      // stage 4 padded rows x 98 cols x 32 ic, swizzled 16B slots (raw bf16)
      const uint4* src = (const uint4*)(inq + (size_t)(b*2 + ch)*PLANE
                                            + (size_t)y0*PX*ICH);
      for (int i = tid; i < 1568; i += 256){
        int r = i / 392, rem = i - r*392;        // 392 uint4 per padded row
        int px = rem >> 2, slot = rem & 3;
        int s = (px & 3) ^ ((px >> 2) & 3);
        *(uint4*)(Bbc + (size_t)r*6272 + (size_t)px*64 + ((slot ^ s)<<4)) = src[i];
      }
    } else {
      // stage from padded bf16 dZq with fused normalize + leaky-relu
      const uint4* src = (const uint4*)(dzq_in + (size_t)(b*2 + ch)*PLANE
                                              + (size_t)y0*PX*ICH);
      for (int i = tid; i < 1568; i += 256){
        int r = i / 392, rem = i - r*392;
        int px = rem >> 2, slot = rem & 3;
        int s = (px & 3) ^ ((px >> 2) & 3);
        int ry = y0 + r;                  // padded row index (0 and 97 are pads)
        uint4 v = src[i];
        union { uint4 v; unsigned short u[8]; } o;
        if (ry >= 1 && ry <= 96 && px >= 1 && px <= 96){
          const unsigned short* hv = (const unsigned short*)&v;
#pragma unroll
          for (int k=0;k<8;k++){
            float2 mr = stat_s[ch*32 + slot*8 + k];
            float f = (float)*(const bf16*)&hv[k];
            float val = (f - mr.x)*mr.y;
            val = (val >= 0.f) ? val : 0.2f*val;
            bf16 hh = (bf16)val;
            o.u[k] = *(unsigned short*)&hh;
          }
        } else {
          o.v = make_uint4(0u,0u,0u,0u);
        }
        *(uint4*)(Bbc + (size_t)r*6272 + (size_t)px*64 + ((slot ^ s)<<4)) = o.v;
      }
    }
    for (int tg = 0; tg < 3; tg++){       // tap row groups (ky = tg)
      __syncthreads();
      { // stage 3 taps x 2 reps x 32 oc (this block's half) x 32 ic, swizzled
        const uint4* srcA = (const uint4*)(apk + (size_t)ch*36864);
        for (int i = tid; i < 768; i += 256){
          int chunk = i >> 7, j = i & 127;       // chunk = tap_r*2+rep, 128 u4/chunk
          int tap_r = chunk >> 1, rep = chunk & 1;
          int oc = j >> 2, slot = j & 3;
          int s = (oc & 3) ^ ((oc >> 2) & 3);
          *(uint4*)(Abc + (size_t)chunk*2048 + (size_t)oc*64 + ((slot ^ s)<<4))
              = srcA[((size_t)((tg*3 + tap_r)*2 + rep))*256 + h*128 + j];
        }
      }
      __syncthreads();
#pragma unroll
      for (int tj = 0; tj < 3; tj++){     // kx = tj
        const int ky = tg, kx = tj;
        bf16x8 Ah[2], Al[2];
#pragma unroll
        for (int mt=0;mt<2;mt++){
          int oc32 = mt*16 + n16;
          int sA = (oc32 & 3) ^ ((oc32 >> 2) & 3);
          Ah[mt] = *(const bf16x8*)(Abc + (size_t)(tj*2 + 0)*2048 + (size_t)oc32*64 + ((q ^ sA)<<4));
          Al[mt] = *(const bf16x8*)(Abc + (size_t)(tj*2 + 1)*2048 + (size_t)oc32*64 + ((q ^ sA)<<4));
        }
        bf16x8 Bf[3];
#pragma unroll
        for (int nt=0;nt<3;nt++){
          int px = wcol + nt*16 + n16 + kx;
          int sB = (px & 3) ^ ((px >> 2) & 3);
          Bf[nt] = *(const bf16x8*)(Bbc + (size_t)(wr + ky)*6272 + (size_t)px*64 + ((q ^ sB)<<4));
        }
#pragma unroll
        for (int nt=0;nt<3;nt++)
#pragma unroll
          for (int mt=0;mt<2;mt++)
            acc[mt][nt] = __builtin_amdgcn_mfma_f32_16x16x32_bf16(Ah[mt], Bf[nt], acc[mt][nt], 0,0,0);
#pragma unroll
        for (int nt=0;nt<3;nt++)
#pragma unroll
          for (int mt=0;mt<2;mt++)
            acc[mt][nt] = __builtin_amdgcn_mfma_f32_16x16x32_bf16(Al[mt], Bf[nt], acc[mt][nt], 0,0,0);
      }
    }
  }

  // ---------------- epilogue ----------------
  if (MODE >= 1){   // yv = -acc (+X at l=7) (+X0 at l=0); coalesced adds (x = lanes)
#pragma unroll
    for (int mt=0;mt<2;mt++)
#pragma unroll
      for (int nt=0;nt<3;nt++){
        const int x = wcol + nt*16 + n16;
#pragma unroll
        for (int r=0;r<4;r++){
          const int oc = h*32 + mt*16 + q*4 + r;
          float v = -acc[mt][nt][r];
          if (Xadd)  v += Xadd[(((size_t)b*64 + oc)*96 + yg)*96 + x];
          if (X0add) v += X0add[((size_t)oc*96 + yg)*96 + x];
          acc[mt][nt][r] = v;
        }
      }
  }
  if (MODE == 2){   // final iter: fused forward scan, fp32 NCHW stores
#pragma unroll
    for (int mt=0;mt<2;mt++)
#pragma unroll
      for (int nt=0;nt<3;nt++){
        const int x = wcol + nt*16 + n16;
#pragma unroll
        for (int r=0;r<4;r++){
          const int oc = h*32 + mt*16 + q*4 + r;
          size_t idx = (((size_t)b*64 + oc)*96 + yg)*96 + x;
          float prev = (b_i != 0.f) ? zb_prev[idx] : 0.f;
          zb_out[idx] = a_i*(b_i*prev + acc[mt][nt][r]);
        }
      }
    return;
  }

  __syncthreads();                        // all waves done with Bbc/Abc
  float* T = (float*)smem + w*1584;       // per-wave 48 x 33 fp32 transpose tile
#pragma unroll
  for (int mt2=0; mt2<2; mt2++)
#pragma unroll
    for (int nt=0;nt<3;nt++)
#pragma unroll
      for (int r=0;r<4;r++)
        T[(nt*16 + n16)*33 + mt2*16 + q*4 + r] = acc[mt2][nt][r];

  float s4[4] = {0.f,0.f,0.f,0.f};        // MODE 0: per-lane stats (acc now dead)
  float q4[4] = {0.f,0.f,0.f,0.f};
  for (int f = lane; f < 384; f += 64){
    int px = f>>3, c4 = (f&7)*4;
    float vv[4];
#pragma unroll
    for (int k=0;k<4;k++) vv[k] = T[px*33 + c4 + k];
    int x = wcol + px;
    if (MODE == 0){
      // store raw dZ as bf16 into the padded layout (stats stay fp32-exact)
      size_t off = ((size_t)(b*2 + h)*PY + (yg+1))*(size_t)PX*ICH
                 + (size_t)(x+1)*ICH + c4;
      union { uint2 v; unsigned short u[4]; } oo;
#pragma unroll
      for (int k=0;k<4;k++){
        bf16 hh = (bf16)vv[k];
        oo.u[k] = *(unsigned short*)&hh;
        s4[k] += vv[k]; q4[k] += vv[k]*vv[k];
      }
      *(uint2*)(dzq_out + off) = oo.v;
    } else {
      size_t off = ((size_t)(b*2 + h)*PY + (yg+1))*(size_t)PX*ICH
                 + (size_t)(x+1)*ICH + c4;
      uint2 pv = *(const uint2*)(yfq_prev + off);
      bf16* ph = (bf16*)&pv;
      union { uint2 v; unsigned short u[4]; } o;
#pragma unroll
      for (int k=0;k<4;k++){
        float yf = a_i*(b_i*(float)ph[k] + vv[k]);
        bf16 hh = (bf16)yf;
        o.u[k] = *(unsigned short*)&hh;
      }
      *(uint2*)(yfq_out + off) = o.v;
    }
  }

  if (MODE == 0){
    // lanes sharing (lane&7) hold partials for the same 4 channels: xor 8/16/32
#pragma unroll
    for (int st = 8; st < 64; st <<= 1)
#pragma unroll
      for (int k=0;k<4;k++){
        s4[k] += __shfl_xor(s4[k], st, 64);
        q4[k] += __shfl_xor(q4[k], st, 64);
      }
    if (lane < 8){
#pragma unroll
      for (int k=0;k<4;k++){
        sred[w][lane*4 + k] = s4[k];
        qred[w][lane*4 + k] = q4[k];
      }
    }
    __syncthreads();
    if (tid < 32){
      float ss = sred[0][tid] + sred[1][tid] + sred[2][tid] + sred[3][tid];
      float qq = qred[0][tid] + qred[1][tid] + qred[2][tid] + qred[3][tid];
      size_t base = ((size_t)b*64 + h*32 + tid)*STAT_STRIDE;
      atomicAdd(&accstat[base], ss);
      atomicAdd(&accstat[base + 16], qq);
    }
  }
}

// ---------------------------------------------------------------------------
extern "C" void kernel_launch(void* const* d_in, const int* in_sizes, int n_in,
                              void* d_out, int out_size, void* d_ws, size_t ws_size,
                              hipStream_t stream) {
  const float* X  = (const float*)d_in[0];
  const float* K  = (const float*)d_in[1];
  const float* X0 = (const float*)d_in[2];

  float* out0  = (float*)d_out;
  float* zbase = out0 + LSTRIDE;

  char* ws = (char*)d_ws;
  float*  statacc = (float*)ws;                         // 24 steps x 64KB padded slots
  bf16*   apf     = (bf16*)(ws + 24*STAT_SLOT*4);
  bf16*   apb     = apf + (size_t)NL*APK_L;
  bf16*   Zq      = apb + (size_t)NL*APK_L;             // 8*PL (doubles as Yfq)
  bf16*   dZq     = Zq + (size_t)NL*PL;                 // PL (padded bf16 dZ)

  hipMemsetAsync(statacc, 0, 24*STAT_SLOT*4, stream);   // all 24 step slots
  hipMemsetAsync(Zq, 0, (size_t)NL*PL*2, stream);       // zero pads (Zq only)

  pack_weights<<<(NL*9*4096 + 255)/256, 256, 0, stream>>>(K, apf, apb);
  init_yf_t<<<dim3(HC, BB), 256, 0, stream>>>(X, X0, Zq);
  back_scan_q<<<PL/8/256, 256, 0, stream>>>(Zq);

  for (int it = 1; it <= 3; it++){
    for (int l = 0; l < NL; l++){
      float* accs = statacc + (size_t)((it-1)*NL + l)*STAT_SLOT;
      conv_mfma<0><<<dim3(48,8,2),256,0,stream>>>(
          Zq + (size_t)l*PL, nullptr, apf + (size_t)l*APK_L,
          dZq, accs, nullptr, nullptr, nullptr, nullptr,
          nullptr, nullptr, 0.f, 0.f);
      float ai = sqrtf((l+1.f)/(l+2.f)), bi = sqrtf((float)l/(float)(l+1));
      if (it < 3)
        conv_mfma<1><<<dim3(48,8,2),256,0,stream>>>(
            nullptr, dZq, apb + (size_t)l*APK_L,
            nullptr, accs, Zq + (size_t)l*PL, Zq + (size_t)(l>0?l-1:0)*PL,
            nullptr, nullptr,
            (l==NL-1)?X:nullptr, (l==0)?X0:nullptr, ai, bi);
      else
        conv_mfma<2><<<dim3(48,8,2),256,0,stream>>>(
            nullptr, dZq, apb + (size_t)l*APK_L,
            nullptr, accs, nullptr, nullptr,
            zbase + (size_t)l*LSTRIDE, zbase + (size_t)(l>0?l-1:0)*LSTRIDE,
            (l==NL-1)?X:nullptr, (l==0)?X0:nullptr, ai, bi);
    }
    if (it < 3) back_scan_q<<<PL/8/256,256,0,stream>>>(Zq);
    else        back_scan_final<<<LSTRIDE/256,256,0,stream>>>(zbase, out0);
  }
}